// Round 1
// baseline (4580.473 us; speedup 1.0000x reference)
//
#include <hip/hip_runtime.h>

// ---------------------------------------------------------------------------
// Transformer (enc-dec, D=512, H=8, N=6, DFF=2048, B=4, S=T=1024, V=32000)
// bf16 MFMA GEMMs with fp32 accumulation; fp32 residual stream / LN / softmax.
// ---------------------------------------------------------------------------

typedef __bf16 bf16x8 __attribute__((ext_vector_type(8)));
typedef __bf16 bf16x4 __attribute__((ext_vector_type(4)));
typedef float  f32x4  __attribute__((ext_vector_type(4)));

__device__ __forceinline__ void gload_lds16(const void* g, void* l) {
  __builtin_amdgcn_global_load_lds((__attribute__((address_space(1))) void*)g,
                                   (__attribute__((address_space(3))) void*)l,
                                   16, 0, 0);
}

// C[M,N] = scale*(A[M,K] @ BT[N,K]^T) + bias, optional ReLU. Batched over z.
// A,BT bf16 row-major; C fp32. Grid: (M/BM, N/BN, batch). 256 threads.
template<int BM, int BN, int BK, bool RELU>
__global__ __launch_bounds__(256)
void gemm_kernel(const __bf16* __restrict__ A, long long sA, int lda,
                 const __bf16* __restrict__ BT, long long sB, int ldb,
                 float* __restrict__ C, long long sC, int ldc,
                 const float* __restrict__ bias, long long sBias,
                 int K, float scale)
{
  constexpr int WM = BM / 2, WN = BN / 2, FM = WM / 16, FN = WN / 16;
  constexpr int LA = (BM * BK) / 2048, LB = (BN * BK) / 2048;
  __shared__ __bf16 lA[BM * BK];
  __shared__ __bf16 lB[BN * BK];
  const int tid  = threadIdx.x;
  const int lane = tid & 63, wave = tid >> 6;
  const int wr = wave >> 1, wc = wave & 1;
  const int bz = blockIdx.z;
  A  += (long long)bz * sA;
  BT += (long long)bz * sB;
  C  += (long long)bz * sC;
  if (bias) bias += (long long)bz * sBias;
  const int bm = blockIdx.x * BM, bn = blockIdx.y * BN;

  f32x4 acc[FM][FN] = {};

  for (int k0 = 0; k0 < K; k0 += BK) {
    __syncthreads();
#pragma unroll
    for (int i = 0; i < LA; i++) {
      int t   = tid + i * 256;
      int row = t / (BK / 8);
      int kc  = (t % (BK / 8)) * 8;
      gload_lds16(A + (long long)(bm + row) * lda + (k0 + kc), lA + t * 8);
    }
#pragma unroll
    for (int i = 0; i < LB; i++) {
      int t   = tid + i * 256;
      int row = t / (BK / 8);
      int kc  = (t % (BK / 8)) * 8;
      gload_lds16(BT + (long long)(bn + row) * ldb + (k0 + kc), lB + t * 8);
    }
    __syncthreads();
#pragma unroll
    for (int kk = 0; kk < BK; kk += 32) {
      bf16x8 af[FM], bfr[FN];
      const int kof = kk + (lane >> 4) * 8;
      const int r16 = lane & 15;
#pragma unroll
      for (int i = 0; i < FM; i++)
        af[i] = *(const bf16x8*)(lA + (wr * WM + i * 16 + r16) * BK + kof);
#pragma unroll
      for (int j = 0; j < FN; j++)
        bfr[j] = *(const bf16x8*)(lB + (wc * WN + j * 16 + r16) * BK + kof);
#pragma unroll
      for (int i = 0; i < FM; i++)
#pragma unroll
        for (int j = 0; j < FN; j++)
          acc[i][j] = __builtin_amdgcn_mfma_f32_16x16x32_bf16(af[i], bfr[j], acc[i][j], 0, 0, 0);
    }
  }

#pragma unroll
  for (int i = 0; i < FM; i++) {
#pragma unroll
    for (int j = 0; j < FN; j++) {
      int row0 = bm + wr * WM + i * 16 + (lane >> 4) * 4;
      int col  = bn + wc * WN + j * 16 + (lane & 15);
      float bv = bias ? bias[col] : 0.f;
#pragma unroll
      for (int r = 0; r < 4; r++) {
        float v = acc[i][j][r] * scale + bv;
        if (RELU) v = fmaxf(v, 0.f);
        C[(long long)(row0 + r) * ldc + col] = v;
      }
    }
  }
}

// W[K,N] fp32 -> WT[N,K] bf16 (batched over z). Block (32,8), grid (N/32,K/32,z).
__global__ void transpose_w_kernel(const float* __restrict__ W, __bf16* __restrict__ WT,
                                   int K, int N)
{
  __shared__ float t[32][33];
  long long mz = (long long)blockIdx.z * K * N;
  W += mz; WT += mz;
  int n0 = blockIdx.x * 32, k0 = blockIdx.y * 32;
  int tx = threadIdx.x, ty = threadIdx.y;
#pragma unroll
  for (int i = 0; i < 32; i += 8)
    t[ty + i][tx] = W[(long long)(k0 + ty + i) * N + (n0 + tx)];
  __syncthreads();
#pragma unroll
  for (int i = 0; i < 32; i += 8)
    WT[(long long)(n0 + ty + i) * K + (k0 + tx)] = (__bf16)t[tx][ty + i];
}

// x = emb[idx] + positional encoding; writes fp32 + bf16. Grid 4096, block 128.
__global__ void embed_kernel(const float* __restrict__ emb, const int* __restrict__ idx,
                             float* __restrict__ X, __bf16* __restrict__ Xb)
{
  int row = blockIdx.x;
  int s   = row & 1023;
  int tok = idx[row];
  int d0  = threadIdx.x * 4;
  float4 e = *(const float4*)(emb + (long long)tok * 512 + d0);
  const float* ep = (const float*)&e;
  float o[4];
#pragma unroll
  for (int j = 0; j < 4; j++) {
    int d = d0 + j;
    float div = expf((float)(d & ~1) * (-9.210340371976184f / 512.f));
    float ang = (float)s * div;
    float pe  = (d & 1) ? cosf(ang) : sinf(ang);
    o[j] = ep[j] + pe;
  }
  *(float4*)(X + (long long)row * 512 + d0) = *(float4*)o;
  bf16x4 ob;
#pragma unroll
  for (int j = 0; j < 4; j++) ob[j] = (__bf16)o[j];
  *(bf16x4*)(Xb + (long long)row * 512 + d0) = ob;
}

// QKV fp32 [3][4096][512] -> per-head bf16: q,k [bh][s][64], v transposed [bh][64][s]
__global__ void reshape_qkv_kernel(const float* __restrict__ QKV,
                                   __bf16* __restrict__ qb, __bf16* __restrict__ kb,
                                   __bf16* __restrict__ vt)
{
  int row = blockIdx.x;
  int b = row >> 10, s = row & 1023;
  for (int e = threadIdx.x; e < 512; e += 256) {
    int h = e >> 6, dk = e & 63;
    long long bh = b * 8 + h;
    long long base = (long long)row * 512 + e;
    qb[(bh << 16) + (s << 6) + dk] = (__bf16)QKV[base];
    kb[(bh << 16) + (s << 6) + dk] = (__bf16)QKV[2097152 + base];
    vt[(bh << 16) + (dk << 10) + s] = (__bf16)QKV[4194304 + base];
  }
}

// masked softmax over a 1024-row; writes bf16 P in place over the fp32 row.
// Safe: every store depends on the full cross-lane reduction of all loads.
__global__ void softmax_kernel(float* __restrict__ SC, const int* __restrict__ mask,
                               int causal, int bh0)
{
  int q = blockIdx.x, bhl = blockIdx.y;
  int lane = threadIdx.x;  // 64
  int b = (bh0 + bhl) >> 3;
  float* srow = SC + ((long long)bhl << 20) + ((long long)q << 10);
  const int* mrow = causal ? (mask + ((long long)q << 10)) : (mask + ((long long)b << 10));
  int k0 = lane * 16;
  float x[16];
#pragma unroll
  for (int j = 0; j < 16; j += 4)
    *(float4*)(x + j) = *(const float4*)(srow + k0 + j);
  float mx = -3e38f;
#pragma unroll
  for (int j = 0; j < 16; j++) {
    if (mrow[k0 + j] == 0) x[j] = -1e9f;
    mx = fmaxf(mx, x[j]);
  }
#pragma unroll
  for (int o = 32; o > 0; o >>= 1) mx = fmaxf(mx, __shfl_xor(mx, o));
  float sum = 0.f;
#pragma unroll
  for (int j = 0; j < 16; j++) { x[j] = expf(x[j] - mx); sum += x[j]; }
#pragma unroll
  for (int o = 32; o > 0; o >>= 1) sum += __shfl_xor(sum, o);
  float inv = 1.f / sum;
  __bf16* prow = (__bf16*)srow;
  bf16x8 p0, p1;
#pragma unroll
  for (int j = 0; j < 8; j++) {
    p0[j] = (__bf16)(x[j] * inv);
    p1[j] = (__bf16)(x[8 + j] * inv);
  }
  *(bf16x8*)(prow + k0)     = p0;
  *(bf16x8*)(prow + k0 + 8) = p1;
}

// Oh fp32 [bh][s][64] -> Ob bf16 [4096][512] (merge heads)
__global__ void reshape_o_kernel(const float* __restrict__ Oh, __bf16* __restrict__ Ob)
{
  int row = blockIdx.x;
  int b = row >> 10, s = row & 1023;
  for (int e = threadIdx.x; e < 512; e += 256) {
    int h = e >> 6, dk = e & 63;
    Ob[(long long)row * 512 + e] = (__bf16)Oh[((long long)(b * 8 + h) << 16) + (s << 6) + dk];
  }
}

// LayerNorm(Xin + Rin) * g + b. One wave per 512-row. Writes fp32 (opt) + bf16.
__global__ void ln_kernel(const float* __restrict__ Xin, const float* __restrict__ Rin,
                          const float* __restrict__ g, const float* __restrict__ b,
                          float* __restrict__ Xout, __bf16* __restrict__ Xbout)
{
  int row = blockIdx.x, lane = threadIdx.x;  // 64
  long long base = (long long)row * 512 + lane * 8;
  float x[8];
  *(float4*)x       = *(const float4*)(Xin + base);
  *(float4*)(x + 4) = *(const float4*)(Xin + base + 4);
  if (Rin) {
    float4 r0 = *(const float4*)(Rin + base);
    float4 r1 = *(const float4*)(Rin + base + 4);
    x[0] += r0.x; x[1] += r0.y; x[2] += r0.z; x[3] += r0.w;
    x[4] += r1.x; x[5] += r1.y; x[6] += r1.z; x[7] += r1.w;
  }
  float s = 0.f;
#pragma unroll
  for (int i = 0; i < 8; i++) s += x[i];
#pragma unroll
  for (int o = 32; o > 0; o >>= 1) s += __shfl_xor(s, o);
  float m = s * (1.f / 512.f);
  float v = 0.f;
#pragma unroll
  for (int i = 0; i < 8; i++) { x[i] -= m; v += x[i] * x[i]; }
#pragma unroll
  for (int o = 32; o > 0; o >>= 1) v += __shfl_xor(v, o);
  float inv = rsqrtf(v * (1.f / 512.f) + 1e-5f);
  int d0 = lane * 8;
  float gg[8], bb[8];
  *(float4*)gg       = *(const float4*)(g + d0);
  *(float4*)(gg + 4) = *(const float4*)(g + d0 + 4);
  *(float4*)bb       = *(const float4*)(b + d0);
  *(float4*)(bb + 4) = *(const float4*)(b + d0 + 4);
  float y[8]; bf16x8 yb;
#pragma unroll
  for (int i = 0; i < 8; i++) {
    y[i] = x[i] * inv * gg[i] + bb[i];
    yb[i] = (__bf16)y[i];
  }
  if (Xout) {
    *(float4*)(Xout + base)     = *(float4*)y;
    *(float4*)(Xout + base + 4) = *(float4*)(y + 4);
  }
  *(bf16x8*)(Xbout + base) = yb;
}

// fp32 -> bf16 convert, 4 elems/thread
__global__ void f2b_kernel(const float* __restrict__ in, __bf16* __restrict__ out, long long n)
{
  long long i = ((long long)blockIdx.x * 256 + threadIdx.x) * 4;
  if (i >= n) return;
  float4 v = *(const float4*)(in + i);
  bf16x4 o;
  o[0] = (__bf16)v.x; o[1] = (__bf16)v.y; o[2] = (__bf16)v.z; o[3] = (__bf16)v.w;
  *(bf16x4*)(out + i) = o;
}

// ---------------------------------------------------------------------------
static void launch_gemm(hipStream_t st, const __bf16* A, long long sA, int lda,
                        const __bf16* BT, long long sB, int ldb,
                        float* C, long long sC, int ldc,
                        const float* bias, long long sBias,
                        int M, int N, int K, float scale, int batch, bool relu, bool bn64)
{
  if (bn64) {
    dim3 g(M / 128, N / 64, batch);
    gemm_kernel<128, 64, 64, false><<<g, 256, 0, st>>>(A, sA, lda, BT, sB, ldb, C, sC, ldc, bias, sBias, K, scale);
  } else if (relu) {
    dim3 g(M / 128, N / 128, batch);
    gemm_kernel<128, 128, 64, true><<<g, 256, 0, st>>>(A, sA, lda, BT, sB, ldb, C, sC, ldc, bias, sBias, K, scale);
  } else {
    dim3 g(M / 128, N / 128, batch);
    gemm_kernel<128, 128, 64, false><<<g, 256, 0, st>>>(A, sA, lda, BT, sB, ldb, C, sC, ldc, bias, sBias, K, scale);
  }
}

extern "C" void kernel_launch(void* const* d_in, const int* in_sizes, int n_in,
                              void* d_out, int out_size, void* d_ws, size_t ws_size,
                              hipStream_t stream)
{
  (void)in_sizes; (void)n_in; (void)out_size; (void)ws_size;
  const float* src_emb    = (const float*)d_in[0];
  const float* tgt_emb    = (const float*)d_in[1];
  const float* enc_attn_w = (const float*)d_in[2];
  const float* enc_attn_b = (const float*)d_in[3];
  const float* enc_ffn_w1 = (const float*)d_in[4];
  const float* enc_ffn_b1 = (const float*)d_in[5];
  const float* enc_ffn_w2 = (const float*)d_in[6];
  const float* enc_ffn_b2 = (const float*)d_in[7];
  const float* enc_ln_g   = (const float*)d_in[8];
  const float* enc_ln_b   = (const float*)d_in[9];
  const float* enc_fg     = (const float*)d_in[10];
  const float* enc_fb     = (const float*)d_in[11];
  const float* dec_self_w = (const float*)d_in[12];
  const float* dec_self_b = (const float*)d_in[13];
  const float* dec_src_w  = (const float*)d_in[14];
  const float* dec_src_b  = (const float*)d_in[15];
  const float* dec_ffn_w1 = (const float*)d_in[16];
  const float* dec_ffn_b1 = (const float*)d_in[17];
  const float* dec_ffn_w2 = (const float*)d_in[18];
  const float* dec_ffn_b2 = (const float*)d_in[19];
  const float* dec_ln_g   = (const float*)d_in[20];
  const float* dec_ln_b   = (const float*)d_in[21];
  const float* dec_fg     = (const float*)d_in[22];
  const float* dec_fb     = (const float*)d_in[23];
  const float* gen_w      = (const float*)d_in[24];
  const float* gen_b      = (const float*)d_in[25];
  const int*   src        = (const int*)d_in[26];
  const int*   tgt        = (const int*)d_in[27];
  const int*   src_mask   = (const int*)d_in[28];
  const int*   tgt_mask   = (const int*)d_in[29];
  float* out = (float*)d_out;

  // ---- workspace layout (~147 MB) ----
  char* wp = (char*)d_ws;
  auto alloc = [&](size_t bytes) { void* p = (void*)wp; wp += (bytes + 255) & ~(size_t)255; return p; };
  __bf16* WT4  = (__bf16*)alloc(4ull * 512 * 512 * 2);   // transposed proj weights [4][N=512][K=512]
  __bf16* WFT  = (__bf16*)alloc(2048ull * 512 * 2);      // transposed ffn weight staging
  float*  X    = (float*) alloc(4096ull * 512 * 4);      // residual stream fp32
  __bf16* Xb   = (__bf16*)alloc(4096ull * 512 * 2);      // bf16 copy (GEMM A)
  __bf16* MEMb = (__bf16*)alloc(4096ull * 512 * 2);      // encoder memory bf16
  float*  R    = (float*) alloc(4096ull * 512 * 4);      // sublayer branch output
  float*  QKV  = (float*) alloc(3ull * 4096 * 512 * 4);  // q,k,v projections fp32
  __bf16* qb   = (__bf16*)alloc(32ull * 1024 * 64 * 2);  // [bh][s][dk]
  __bf16* kb   = (__bf16*)alloc(32ull * 1024 * 64 * 2);  // [bh][s][dk]
  __bf16* vt   = (__bf16*)alloc(32ull * 1024 * 64 * 2);  // [bh][dk][s]
  float*  Oh   = (float*) alloc(32ull * 1024 * 64 * 4);  // attn out per head fp32
  __bf16* Ob   = (__bf16*)alloc(4096ull * 512 * 2);      // merged attn out bf16
  float*  BIG  = (float*) alloc(67108864);               // union region:
  float*  SC   = BIG;                                    //  scores 16bh chunk fp32 (P bf16 aliased)
  float*  F    = BIG;                                    //  ffn hidden fp32 [4096][2048]
  __bf16* Fb   = (__bf16*)((char*)BIG + 33554432);       //  ffn hidden bf16
  __bf16* GENT = (__bf16*)BIG;                           //  gen_w^T bf16 [32000][512]

  // attention sublayer: assumes WT4 holds 4 transposed weights; writes R.
  auto attention = [&](const float* bptr, const int* mask, int causal,
                       const __bf16* Aq, const __bf16* Akv) {
    if (Aq == Akv) {
      launch_gemm(stream, Aq, 0, 512, WT4, 262144, 512, QKV, 2097152, 512,
                  bptr, 512, 4096, 512, 512, 1.f, 3, false, false);
    } else {
      launch_gemm(stream, Aq, 0, 512, WT4, 0, 512, QKV, 0, 512,
                  bptr, 0, 4096, 512, 512, 1.f, 1, false, false);
      launch_gemm(stream, Akv, 0, 512, WT4 + 262144, 262144, 512, QKV + 2097152, 2097152, 512,
                  bptr + 512, 512, 4096, 512, 512, 1.f, 2, false, false);
    }
    reshape_qkv_kernel<<<4096, 256, 0, stream>>>(QKV, qb, kb, vt);
    for (int half = 0; half < 2; half++) {
      long long z0 = (long long)half * 16;
      launch_gemm(stream, qb + z0 * 65536, 65536, 64, kb + z0 * 65536, 65536, 64,
                  SC, 1048576, 1024, nullptr, 0, 1024, 1024, 64, 0.125f, 16, false, false);
      softmax_kernel<<<dim3(1024, 16), 64, 0, stream>>>(SC, mask, causal, (int)z0);
      launch_gemm(stream, (const __bf16*)SC, 2097152, 2048, vt + z0 * 65536, 65536, 1024,
                  Oh + z0 * 65536, 65536, 64, nullptr, 0, 1024, 64, 1024, 1.f, 16, false, true);
    }
    reshape_o_kernel<<<4096, 256, 0, stream>>>(Oh, Ob);
    launch_gemm(stream, Ob, 0, 512, WT4 + 3 * 262144, 0, 512, R, 0, 512,
                bptr + 3 * 512, 0, 4096, 512, 512, 1.f, 1, false, false);
  };

  auto ffn = [&](const float* w1, const float* b1, const float* w2, const float* b2) {
    transpose_w_kernel<<<dim3(64, 16, 1), dim3(32, 8), 0, stream>>>(w1, WFT, 512, 2048);
    launch_gemm(stream, Xb, 0, 512, WFT, 0, 512, F, 0, 2048,
                b1, 0, 4096, 2048, 512, 1.f, 1, true, false);
    f2b_kernel<<<8192, 256, 0, stream>>>(F, Fb, 8388608LL);
    transpose_w_kernel<<<dim3(16, 64, 1), dim3(32, 8), 0, stream>>>(w2, WFT, 2048, 512);
    launch_gemm(stream, Fb, 0, 2048, WFT, 0, 2048, R, 0, 512,
                b2, 0, 4096, 512, 2048, 1.f, 1, false, false);
  };

  // ---------------- encoder ----------------
  embed_kernel<<<4096, 128, 0, stream>>>(src_emb, src, X, Xb);
  for (int i = 0; i < 6; i++) {
    transpose_w_kernel<<<dim3(16, 16, 4), dim3(32, 8), 0, stream>>>(
        enc_attn_w + (long long)i * 1048576, WT4, 512, 512);
    attention(enc_attn_b + i * 2048, src_mask, 0, Xb, Xb);
    ln_kernel<<<4096, 64, 0, stream>>>(X, R, enc_ln_g + i * 1024, enc_ln_b + i * 1024, X, Xb);
    ffn(enc_ffn_w1 + (long long)i * 1048576, enc_ffn_b1 + i * 2048,
        enc_ffn_w2 + (long long)i * 1048576, enc_ffn_b2 + i * 512);
    ln_kernel<<<4096, 64, 0, stream>>>(X, R, enc_ln_g + i * 1024 + 512, enc_ln_b + i * 1024 + 512, X, Xb);
  }
  ln_kernel<<<4096, 64, 0, stream>>>(X, nullptr, enc_fg, enc_fb, nullptr, MEMb);

  // ---------------- decoder ----------------
  embed_kernel<<<4096, 128, 0, stream>>>(tgt_emb, tgt, X, Xb);
  for (int i = 0; i < 6; i++) {
    transpose_w_kernel<<<dim3(16, 16, 4), dim3(32, 8), 0, stream>>>(
        dec_self_w + (long long)i * 1048576, WT4, 512, 512);
    attention(dec_self_b + i * 2048, tgt_mask, 1, Xb, Xb);
    ln_kernel<<<4096, 64, 0, stream>>>(X, R, dec_ln_g + i * 1536, dec_ln_b + i * 1536, X, Xb);

    transpose_w_kernel<<<dim3(16, 16, 4), dim3(32, 8), 0, stream>>>(
        dec_src_w + (long long)i * 1048576, WT4, 512, 512);
    attention(dec_src_b + i * 2048, src_mask, 0, Xb, MEMb);
    ln_kernel<<<4096, 64, 0, stream>>>(X, R, dec_ln_g + i * 1536 + 512, dec_ln_b + i * 1536 + 512, X, Xb);

    ffn(dec_ffn_w1 + (long long)i * 1048576, dec_ffn_b1 + i * 2048,
        dec_ffn_w2 + (long long)i * 1048576, dec_ffn_b2 + i * 512);
    ln_kernel<<<4096, 64, 0, stream>>>(X, R, dec_ln_g + i * 1536 + 1024, dec_ln_b + i * 1536 + 1024, X, Xb);
  }
  ln_kernel<<<4096, 64, 0, stream>>>(X, nullptr, dec_fg, dec_fb, nullptr, Xb);

  // ---------------- generator ----------------
  transpose_w_kernel<<<dim3(1000, 16, 1), dim3(32, 8), 0, stream>>>(gen_w, GENT, 512, 32000);
  launch_gemm(stream, Xb, 0, 512, GENT, 0, 512, out, 0, 32000,
              gen_b, 0, 4096, 32000, 512, 1.f, 1, false, false);
}

// Round 2
// 2491.537 us; speedup vs baseline: 1.8384x; 1.8384x over previous
//
#include <hip/hip_runtime.h>

// ---------------------------------------------------------------------------
// Transformer (enc-dec, D=512, H=8, N=6, DFF=2048, B=4, S=T=1024, V=32000)
// bf16 MFMA GEMMs with fp32 accumulation; fused flash attention;
// fp32 residual stream / LN; fused epilogues (qkv-head write, bf16+relu).
// ---------------------------------------------------------------------------

typedef __bf16 bf16x8 __attribute__((ext_vector_type(8)));
typedef __bf16 bf16x4 __attribute__((ext_vector_type(4)));
typedef float  f32x4  __attribute__((ext_vector_type(4)));

__device__ __forceinline__ void gload_lds16(const void* g, void* l) {
  __builtin_amdgcn_global_load_lds((__attribute__((address_space(1))) void*)g,
                                   (__attribute__((address_space(3))) void*)l,
                                   16, 0, 0);
}

// ---------------------------------------------------------------------------
// GEMM: C = A[M,K] @ BT[N,K]^T + bias. A,BT bf16 row-major. 256 thr, 4 waves.
// EPI 0: C fp32.  EPI 1: C bf16 + ReLU.  EPI 2: write qb/kb/vt head layouts.
template<int BM, int BN, int BK, int EPI>
__global__ __launch_bounds__(256)
void gemm_kernel(const __bf16* __restrict__ A, long long sA, int lda,
                 const __bf16* __restrict__ BT, long long sB, int ldb,
                 void* __restrict__ Cv, long long sC, int ldc,
                 const float* __restrict__ bias, long long sBias,
                 int K, __bf16* __restrict__ qb, __bf16* __restrict__ kb,
                 __bf16* __restrict__ vt, int zoff)
{
  constexpr int WM = BM / 2, WN = BN / 2, FM = WM / 16, FN = WN / 16;
  constexpr int LA = (BM * BK) / 2048, LB = (BN * BK) / 2048;
  __shared__ __bf16 lA[BM * BK];
  __shared__ __bf16 lB[BN * BK];
  const int tid  = threadIdx.x;
  const int lane = tid & 63, wave = tid >> 6;
  const int wr = wave >> 1, wc = wave & 1;
  const int bz = blockIdx.z;
  A  += (long long)bz * sA;
  BT += (long long)bz * sB;
  if (bias) bias += (long long)bz * sBias;
  const int bm = blockIdx.x * BM, bn = blockIdx.y * BN;

  f32x4 acc[FM][FN] = {};

  for (int k0 = 0; k0 < K; k0 += BK) {
    __syncthreads();
#pragma unroll
    for (int i = 0; i < LA; i++) {
      int t   = tid + i * 256;
      int row = t / (BK / 8);
      int kc  = (t % (BK / 8)) * 8;
      gload_lds16(A + (long long)(bm + row) * lda + (k0 + kc), lA + t * 8);
    }
#pragma unroll
    for (int i = 0; i < LB; i++) {
      int t   = tid + i * 256;
      int row = t / (BK / 8);
      int kc  = (t % (BK / 8)) * 8;
      gload_lds16(BT + (long long)(bn + row) * ldb + (k0 + kc), lB + t * 8);
    }
    __syncthreads();
#pragma unroll
    for (int kk = 0; kk < BK; kk += 32) {
      bf16x8 af[FM], bfr[FN];
      const int kof = kk + (lane >> 4) * 8;
      const int r16 = lane & 15;
#pragma unroll
      for (int i = 0; i < FM; i++)
        af[i] = *(const bf16x8*)(lA + (wr * WM + i * 16 + r16) * BK + kof);
#pragma unroll
      for (int j = 0; j < FN; j++)
        bfr[j] = *(const bf16x8*)(lB + (wc * WN + j * 16 + r16) * BK + kof);
#pragma unroll
      for (int i = 0; i < FM; i++)
#pragma unroll
        for (int j = 0; j < FN; j++)
          acc[i][j] = __builtin_amdgcn_mfma_f32_16x16x32_bf16(af[i], bfr[j], acc[i][j], 0, 0, 0);
    }
  }

#pragma unroll
  for (int i = 0; i < FM; i++) {
#pragma unroll
    for (int j = 0; j < FN; j++) {
      int row0 = bm + wr * WM + i * 16 + (lane >> 4) * 4;
      int col  = bn + wc * WN + j * 16 + (lane & 15);
      float bv = bias ? bias[col] : 0.f;
      if constexpr (EPI == 2) {
        int z = bz + zoff;
        int b = row0 >> 10, s = row0 & 1023;
        int h = col >> 6, dk = col & 63;
        long long bh = b * 8 + h;
        if (z == 2) {
          bf16x4 vv;
#pragma unroll
          for (int r = 0; r < 4; r++) vv[r] = (__bf16)(acc[i][j][r] + bv);
          *(bf16x4*)(vt + (bh << 16) + (dk << 10) + s) = vv;
        } else {
          __bf16* dst = (z == 0) ? qb : kb;
          float sc = (z == 0) ? 0.125f : 1.0f;
#pragma unroll
          for (int r = 0; r < 4; r++)
            dst[(bh << 16) + ((long long)(s + r) << 6) + dk] = (__bf16)((acc[i][j][r] + bv) * sc);
        }
      } else if constexpr (EPI == 1) {
        __bf16* C = (__bf16*)Cv;
        C += (long long)bz * sC;
#pragma unroll
        for (int r = 0; r < 4; r++)
          C[(long long)(row0 + r) * ldc + col] = (__bf16)fmaxf(acc[i][j][r] + bv, 0.f);
      } else {
        float* C = (float*)Cv;
        C += (long long)bz * sC;
#pragma unroll
        for (int r = 0; r < 4; r++)
          C[(long long)(row0 + r) * ldc + col] = acc[i][j][r] + bv;
      }
    }
  }
}

// ---------------------------------------------------------------------------
// Flash attention: per block one (bh, 64-row q-tile); 4 waves, 16 q-rows each.
// qb,kb: [bh][1024][64] bf16 (q pre-scaled by 1/8); vt: [bh][64][1024] bf16.
// KV tiles of 128, K/V staged in XOR-swizzled LDS; online softmax; P via
// per-wave swizzled LDS; output merged-head bf16 [4096][512].
template<int CAUSAL>
__global__ __launch_bounds__(256)
void flash_kernel(const __bf16* __restrict__ qb, const __bf16* __restrict__ kb,
                  const __bf16* __restrict__ vt, const int* __restrict__ smask,
                  __bf16* __restrict__ Ob)
{
  __shared__ __bf16 lK[128 * 64];   // swizzled [128 k][64 d]
  __shared__ __bf16 lV[64 * 128];   // swizzled [64 d][128 k]
  __shared__ __bf16 lP[4][16 * 128];// per-wave swizzled [16 q][128 k]
  const int bh = blockIdx.y;
  const int b = bh >> 3, h = bh & 7;
  const int q0 = blockIdx.x * 64;
  const int tid = threadIdx.x, lane = tid & 63, w = tid >> 6;
  const char* kh = (const char*)(kb + ((long long)bh << 16));
  const char* vh = (const char*)(vt + ((long long)bh << 16));

  // Q fragments (A-operand): rows q0 + w*16 + (lane&15), k-slice (lane>>4)*8
  bf16x8 qa[2];
  {
    const __bf16* qrow = qb + ((long long)bh << 16)
                       + (long long)(q0 + w * 16 + (lane & 15)) * 64 + (lane >> 4) * 8;
    qa[0] = *(const bf16x8*)(qrow);
    qa[1] = *(const bf16x8*)(qrow + 32);
  }
  f32x4 oacc[4] = {};
  float m[4], l[4];
#pragma unroll
  for (int r = 0; r < 4; r++) { m[r] = -3e38f; l[r] = 0.f; }

  const int nt = CAUSAL ? (blockIdx.x / 2 + 1) : 8;
  char* lPw = (char*)lP + w * 4096;

  for (int t = 0; t < nt; t++) {
    const int k0 = t * 128;
    __syncthreads();  // previous tile's compute done before restage
#pragma unroll
    for (int i = 0; i < 4; i++) {  // K tile: 128 rows x 128B
      int c = tid + i * 256;
      int row = c >> 3, cb = (c & 7) << 4;
      int cl = cb ^ ((row & 7) << 4);
      gload_lds16(kh + (long long)(k0 + row) * 128 + cl, (char*)lK + c * 16);
    }
#pragma unroll
    for (int i = 0; i < 4; i++) {  // V^T tile: 64 rows x 256B slice
      int c = tid + i * 256;
      int row = c >> 4, cb = (c & 15) << 4;
      int cl = cb ^ ((row & 7) << 4);
      gload_lds16(vh + (long long)row * 2048 + (long long)k0 * 2 + cl, (char*)lV + c * 16);
    }
    __syncthreads();  // staged tiles visible (barrier drains vmcnt)

    // ---- S = Q @ K^T (per wave: 16 rows x 128 cols, 8 col-frags) ----
    f32x4 sf[8];
#pragma unroll
    for (int f = 0; f < 8; f++) {
      int row = f * 16 + (lane & 15);
      f32x4 s = {};
#pragma unroll
      for (int ks = 0; ks < 2; ks++) {
        int cb = ks * 64 + (lane >> 4) * 16;
        bf16x8 kf = *(const bf16x8*)((char*)lK + row * 128 + (cb ^ ((row & 7) << 4)));
        s = __builtin_amdgcn_mfma_f32_16x16x32_bf16(qa[ks], kf, s, 0, 0, 0);
      }
      sf[f] = s;
    }

    // ---- masking ----
    if (!CAUSAL) {
#pragma unroll
      for (int f = 0; f < 8; f++) {
        if (smask[b * 1024 + k0 + f * 16 + (lane & 15)] == 0) {
#pragma unroll
          for (int r = 0; r < 4; r++) sf[f][r] = -1e30f;
        }
      }
    } else if (t == nt - 1) {
#pragma unroll
      for (int f = 0; f < 8; f++) {
        int kc = k0 + f * 16 + (lane & 15);
#pragma unroll
        for (int r = 0; r < 4; r++) {
          int qr = q0 + w * 16 + (lane >> 4) * 4 + r;
          if (kc > qr) sf[f][r] = -1e30f;
        }
      }
    }

    // ---- online softmax ----
    float mt[4], mn[4], cr[4], rs[4];
#pragma unroll
    for (int r = 0; r < 4; r++) {
      float v = sf[0][r];
#pragma unroll
      for (int f = 1; f < 8; f++) v = fmaxf(v, sf[f][r]);
      mt[r] = v;
    }
#pragma unroll
    for (int o = 1; o < 16; o <<= 1)
#pragma unroll
      for (int r = 0; r < 4; r++) mt[r] = fmaxf(mt[r], __shfl_xor(mt[r], o));
#pragma unroll
    for (int r = 0; r < 4; r++) {
      mn[r] = fmaxf(m[r], mt[r]);
      cr[r] = __expf(m[r] - mn[r]);
      m[r]  = mn[r];
      rs[r] = 0.f;
    }
#pragma unroll
    for (int f = 0; f < 8; f++)
#pragma unroll
      for (int r = 0; r < 4; r++) {
        float p = __expf(sf[f][r] - mn[r]);
        sf[f][r] = p;
        rs[r] += p;
      }
#pragma unroll
    for (int o = 1; o < 16; o <<= 1)
#pragma unroll
      for (int r = 0; r < 4; r++) rs[r] += __shfl_xor(rs[r], o);
#pragma unroll
    for (int r = 0; r < 4; r++) l[r] = l[r] * cr[r] + rs[r];
#pragma unroll
    for (int d = 0; d < 4; d++)
#pragma unroll
      for (int r = 0; r < 4; r++) oacc[d][r] *= cr[r];

    // ---- write P to per-wave swizzled LDS ----
#pragma unroll
    for (int f = 0; f < 8; f++) {
      int colB = f * 32 + (lane & 15) * 2;
#pragma unroll
      for (int r = 0; r < 4; r++) {
        int row = (lane >> 4) * 4 + r;
        *(__bf16*)(lPw + row * 256 + (colB ^ ((row & 7) << 4))) = (__bf16)sf[f][r];
      }
    }
    asm volatile("s_waitcnt lgkmcnt(0)" ::: "memory");

    // ---- O += P @ V ----
#pragma unroll
    for (int ks = 0; ks < 4; ks++) {
      int prow = lane & 15;
      int cb = ks * 64 + (lane >> 4) * 16;
      bf16x8 pa = *(const bf16x8*)(lPw + prow * 256 + (cb ^ ((prow & 7) << 4)));
#pragma unroll
      for (int d = 0; d < 4; d++) {
        int vrow = d * 16 + (lane & 15);
        bf16x8 vf = *(const bf16x8*)((char*)lV + vrow * 256 + (cb ^ ((vrow & 7) << 4)));
        oacc[d] = __builtin_amdgcn_mfma_f32_16x16x32_bf16(pa, vf, oacc[d], 0, 0, 0);
      }
    }
  }

  // ---- epilogue: O = acc / l, write merged-head bf16 ----
  float inv[4];
#pragma unroll
  for (int r = 0; r < 4; r++) inv[r] = 1.f / l[r];
#pragma unroll
  for (int d = 0; d < 4; d++)
#pragma unroll
    for (int r = 0; r < 4; r++) {
      long long row = b * 1024 + q0 + w * 16 + (lane >> 4) * 4 + r;
      Ob[row * 512 + h * 64 + d * 16 + (lane & 15)] = (__bf16)(oacc[d][r] * inv[r]);
    }
}

// ---------------------------------------------------------------------------
// W[K,N] fp32 -> WT[N,K] bf16 (batched over z). Block (32,8), grid (N/32,K/32,z).
__global__ void transpose_w_kernel(const float* __restrict__ W, __bf16* __restrict__ WT,
                                   int K, int N)
{
  __shared__ float t[32][33];
  long long mz = (long long)blockIdx.z * K * N;
  W += mz; WT += mz;
  int n0 = blockIdx.x * 32, k0 = blockIdx.y * 32;
  int tx = threadIdx.x, ty = threadIdx.y;
#pragma unroll
  for (int i = 0; i < 32; i += 8)
    t[ty + i][tx] = W[(long long)(k0 + ty + i) * N + (n0 + tx)];
  __syncthreads();
#pragma unroll
  for (int i = 0; i < 32; i += 8)
    WT[(long long)(n0 + ty + i) * K + (k0 + tx)] = (__bf16)t[tx][ty + i];
}

// x = emb[idx] + positional encoding; writes fp32 + bf16. Grid 4096, block 128.
__global__ void embed_kernel(const float* __restrict__ emb, const int* __restrict__ idx,
                             float* __restrict__ X, __bf16* __restrict__ Xb)
{
  int row = blockIdx.x;
  int s   = row & 1023;
  int tok = idx[row];
  int d0  = threadIdx.x * 4;
  float4 e = *(const float4*)(emb + (long long)tok * 512 + d0);
  const float* ep = (const float*)&e;
  float o[4];
#pragma unroll
  for (int j = 0; j < 4; j++) {
    int d = d0 + j;
    float div = expf((float)(d & ~1) * (-9.210340371976184f / 512.f));
    float ang = (float)s * div;
    float pe  = (d & 1) ? cosf(ang) : sinf(ang);
    o[j] = ep[j] + pe;
  }
  *(float4*)(X + (long long)row * 512 + d0) = *(float4*)o;
  bf16x4 ob;
#pragma unroll
  for (int j = 0; j < 4; j++) ob[j] = (__bf16)o[j];
  *(bf16x4*)(Xb + (long long)row * 512 + d0) = ob;
}

// LayerNorm(Xin + Rin) * g + b. One wave per 512-row. Writes fp32 (opt) + bf16.
__global__ void ln_kernel(const float* __restrict__ Xin, const float* __restrict__ Rin,
                          const float* __restrict__ g, const float* __restrict__ b,
                          float* __restrict__ Xout, __bf16* __restrict__ Xbout)
{
  int row = blockIdx.x, lane = threadIdx.x;  // 64
  long long base = (long long)row * 512 + lane * 8;
  float x[8];
  *(float4*)x       = *(const float4*)(Xin + base);
  *(float4*)(x + 4) = *(const float4*)(Xin + base + 4);
  if (Rin) {
    float4 r0 = *(const float4*)(Rin + base);
    float4 r1 = *(const float4*)(Rin + base + 4);
    x[0] += r0.x; x[1] += r0.y; x[2] += r0.z; x[3] += r0.w;
    x[4] += r1.x; x[5] += r1.y; x[6] += r1.z; x[7] += r1.w;
  }
  float s = 0.f;
#pragma unroll
  for (int i = 0; i < 8; i++) s += x[i];
#pragma unroll
  for (int o = 32; o > 0; o >>= 1) s += __shfl_xor(s, o);
  float mean = s * (1.f / 512.f);
  float v = 0.f;
#pragma unroll
  for (int i = 0; i < 8; i++) { x[i] -= mean; v += x[i] * x[i]; }
#pragma unroll
  for (int o = 32; o > 0; o >>= 1) v += __shfl_xor(v, o);
  float inv = rsqrtf(v * (1.f / 512.f) + 1e-5f);
  int d0 = lane * 8;
  float gg[8], bb[8];
  *(float4*)gg       = *(const float4*)(g + d0);
  *(float4*)(gg + 4) = *(const float4*)(g + d0 + 4);
  *(float4*)bb       = *(const float4*)(b + d0);
  *(float4*)(bb + 4) = *(const float4*)(b + d0 + 4);
  float y[8]; bf16x8 yb;
#pragma unroll
  for (int i = 0; i < 8; i++) {
    y[i] = x[i] * inv * gg[i] + bb[i];
    yb[i] = (__bf16)y[i];
  }
  if (Xout) {
    *(float4*)(Xout + base)     = *(float4*)y;
    *(float4*)(Xout + base + 4) = *(float4*)(y + 4);
  }
  *(bf16x8*)(Xbout + base) = yb;
}

// ---------------------------------------------------------------------------
extern "C" void kernel_launch(void* const* d_in, const int* in_sizes, int n_in,
                              void* d_out, int out_size, void* d_ws, size_t ws_size,
                              hipStream_t stream)
{
  (void)in_sizes; (void)n_in; (void)out_size; (void)ws_size;
  const float* src_emb    = (const float*)d_in[0];
  const float* tgt_emb    = (const float*)d_in[1];
  const float* enc_attn_w = (const float*)d_in[2];
  const float* enc_attn_b = (const float*)d_in[3];
  const float* enc_ffn_w1 = (const float*)d_in[4];
  const float* enc_ffn_b1 = (const float*)d_in[5];
  const float* enc_ffn_w2 = (const float*)d_in[6];
  const float* enc_ffn_b2 = (const float*)d_in[7];
  const float* enc_ln_g   = (const float*)d_in[8];
  const float* enc_ln_b   = (const float*)d_in[9];
  const float* enc_fg     = (const float*)d_in[10];
  const float* enc_fb     = (const float*)d_in[11];
  const float* dec_self_w = (const float*)d_in[12];
  const float* dec_self_b = (const float*)d_in[13];
  const float* dec_src_w  = (const float*)d_in[14];
  const float* dec_src_b  = (const float*)d_in[15];
  const float* dec_ffn_w1 = (const float*)d_in[16];
  const float* dec_ffn_b1 = (const float*)d_in[17];
  const float* dec_ffn_w2 = (const float*)d_in[18];
  const float* dec_ffn_b2 = (const float*)d_in[19];
  const float* dec_ln_g   = (const float*)d_in[20];
  const float* dec_ln_b   = (const float*)d_in[21];
  const float* dec_fg     = (const float*)d_in[22];
  const float* dec_fb     = (const float*)d_in[23];
  const float* gen_w      = (const float*)d_in[24];
  const float* gen_b      = (const float*)d_in[25];
  const int*   src        = (const int*)d_in[26];
  const int*   tgt        = (const int*)d_in[27];
  const int*   src_mask   = (const int*)d_in[28];

  float* out = (float*)d_out;

  // ---- workspace (~92 MB) ----
  char* wp = (char*)d_ws;
  auto alloc = [&](size_t bytes) { void* p = (void*)wp; wp += (bytes + 255) & ~(size_t)255; return p; };
  __bf16* WT4  = (__bf16*)alloc(4ull * 512 * 512 * 2);
  __bf16* WFT  = (__bf16*)alloc(2048ull * 512 * 2);
  float*  X    = (float*) alloc(4096ull * 512 * 4);
  __bf16* Xb   = (__bf16*)alloc(4096ull * 512 * 2);
  __bf16* MEMb = (__bf16*)alloc(4096ull * 512 * 2);
  float*  R    = (float*) alloc(4096ull * 512 * 4);
  __bf16* qb   = (__bf16*)alloc(32ull * 1024 * 64 * 2);
  __bf16* kb   = (__bf16*)alloc(32ull * 1024 * 64 * 2);
  __bf16* vt   = (__bf16*)alloc(32ull * 1024 * 64 * 2);
  __bf16* Ob   = (__bf16*)alloc(4096ull * 512 * 2);
  __bf16* Fb   = (__bf16*)alloc(4096ull * 2048 * 2);
  __bf16* GENT = (__bf16*)alloc(32000ull * 512 * 2);

  // attention: WT4 holds the 4 transposed weights; writes R.
  auto attention = [&](const float* bptr, int causal, const __bf16* Aq, const __bf16* Akv) {
    if (Aq == Akv) {
      gemm_kernel<128, 64, 64, 2><<<dim3(32, 8, 3), 256, 0, stream>>>(
          Aq, 0, 512, WT4, 262144, 512, nullptr, 0, 0, bptr, 512, 512, qb, kb, vt, 0);
    } else {
      gemm_kernel<128, 64, 64, 2><<<dim3(32, 8, 1), 256, 0, stream>>>(
          Aq, 0, 512, WT4, 0, 512, nullptr, 0, 0, bptr, 0, 512, qb, kb, vt, 0);
      gemm_kernel<128, 64, 64, 2><<<dim3(32, 8, 2), 256, 0, stream>>>(
          Akv, 0, 512, WT4 + 262144, 262144, 512, nullptr, 0, 0, bptr + 512, 512, 512, qb, kb, vt, 1);
    }
    if (causal)
      flash_kernel<1><<<dim3(16, 32), 256, 0, stream>>>(qb, kb, vt, nullptr, Ob);
    else
      flash_kernel<0><<<dim3(16, 32), 256, 0, stream>>>(qb, kb, vt, src_mask, Ob);
    gemm_kernel<128, 64, 64, 0><<<dim3(32, 8, 1), 256, 0, stream>>>(
        Ob, 0, 512, WT4 + 3 * 262144, 0, 512, R, 0, 512, bptr + 3 * 512, 0, 512,
        nullptr, nullptr, nullptr, 0);
  };

  auto ffn = [&](const float* w1, const float* b1, const float* w2, const float* b2) {
    transpose_w_kernel<<<dim3(64, 16, 1), dim3(32, 8), 0, stream>>>(w1, WFT, 512, 2048);
    gemm_kernel<128, 128, 64, 1><<<dim3(32, 16, 1), 256, 0, stream>>>(
        Xb, 0, 512, WFT, 0, 512, Fb, 0, 2048, b1, 0, 512, nullptr, nullptr, nullptr, 0);
    transpose_w_kernel<<<dim3(16, 64, 1), dim3(32, 8), 0, stream>>>(w2, WFT, 2048, 512);
    gemm_kernel<128, 64, 64, 0><<<dim3(32, 8, 1), 256, 0, stream>>>(
        Fb, 0, 2048, WFT, 0, 2048, R, 0, 512, b2, 0, 2048, nullptr, nullptr, nullptr, 0);
  };

  // ---------------- encoder ----------------
  embed_kernel<<<4096, 128, 0, stream>>>(src_emb, src, X, Xb);
  for (int i = 0; i < 6; i++) {
    transpose_w_kernel<<<dim3(16, 16, 4), dim3(32, 8), 0, stream>>>(
        enc_attn_w + (long long)i * 1048576, WT4, 512, 512);
    attention(enc_attn_b + i * 2048, 0, Xb, Xb);
    ln_kernel<<<4096, 64, 0, stream>>>(X, R, enc_ln_g + i * 1024, enc_ln_b + i * 1024, X, Xb);
    ffn(enc_ffn_w1 + (long long)i * 1048576, enc_ffn_b1 + i * 2048,
        enc_ffn_w2 + (long long)i * 1048576, enc_ffn_b2 + i * 512);
    ln_kernel<<<4096, 64, 0, stream>>>(X, R, enc_ln_g + i * 1024 + 512, enc_ln_b + i * 1024 + 512, X, Xb);
  }
  ln_kernel<<<4096, 64, 0, stream>>>(X, nullptr, enc_fg, enc_fb, nullptr, MEMb);

  // ---------------- decoder ----------------
  embed_kernel<<<4096, 128, 0, stream>>>(tgt_emb, tgt, X, Xb);
  for (int i = 0; i < 6; i++) {
    transpose_w_kernel<<<dim3(16, 16, 4), dim3(32, 8), 0, stream>>>(
        dec_self_w + (long long)i * 1048576, WT4, 512, 512);
    attention(dec_self_b + i * 2048, 1, Xb, Xb);
    ln_kernel<<<4096, 64, 0, stream>>>(X, R, dec_ln_g + i * 1536, dec_ln_b + i * 1536, X, Xb);

    transpose_w_kernel<<<dim3(16, 16, 4), dim3(32, 8), 0, stream>>>(
        dec_src_w + (long long)i * 1048576, WT4, 512, 512);
    attention(dec_src_b + i * 2048, 0, Xb, MEMb);
    ln_kernel<<<4096, 64, 0, stream>>>(X, R, dec_ln_g + i * 1536 + 512, dec_ln_b + i * 1536 + 512, X, Xb);

    ffn(dec_ffn_w1 + (long long)i * 1048576, dec_ffn_b1 + i * 2048,
        dec_ffn_w2 + (long long)i * 1048576, dec_ffn_b2 + i * 512);
    ln_kernel<<<4096, 64, 0, stream>>>(X, R, dec_ln_g + i * 1536 + 1024, dec_ln_b + i * 1536 + 1024, X, Xb);
  }
  ln_kernel<<<4096, 64, 0, stream>>>(X, nullptr, dec_fg, dec_fb, nullptr, Xb);

  // ---------------- generator ----------------
  transpose_w_kernel<<<dim3(1000, 16, 1), dim3(32, 8), 0, stream>>>(gen_w, GENT, 512, 32000);
  gemm_kernel<128, 128, 64, 0><<<dim3(32, 250, 1), 256, 0, stream>>>(
      Xb, 0, 512, GENT, 0, 512, out, 0, 32000, gen_b, 0, 512, nullptr, nullptr, nullptr, 0);
}

// Round 3
// 2466.553 us; speedup vs baseline: 1.8570x; 1.0101x over previous
//
#include <hip/hip_runtime.h>

// ---------------------------------------------------------------------------
// Transformer (enc-dec, D=512, H=8, N=6, DFF=2048, B=4, S=T=1024, V=32000)
// bf16 MFMA GEMMs with fp32 accumulation; double-buffered LDS staging (T3-min
// 2-phase); fused flash attention; fp32 residual stream / LN; up-front bulk
// weight transposes.
// ---------------------------------------------------------------------------

typedef __bf16 bf16x8 __attribute__((ext_vector_type(8)));
typedef __bf16 bf16x4 __attribute__((ext_vector_type(4)));
typedef float  f32x4  __attribute__((ext_vector_type(4)));

__device__ __forceinline__ void gload_lds16(const void* g, void* l) {
  __builtin_amdgcn_global_load_lds((__attribute__((address_space(1))) void*)g,
                                   (__attribute__((address_space(3))) void*)l,
                                   16, 0, 0);
}

// ---------------------------------------------------------------------------
// GEMM: C = A[M,K] @ BT[N,K]^T + bias. A,BT bf16 row-major. 256 thr, 4 waves.
// Double-buffered: stage(t+1) issued before compute(t); one barrier per tile.
// EPI 0: C fp32.  EPI 1: C bf16 + ReLU.  EPI 2: write qb/kb/vt head layouts.
template<int BM, int BN, int BK, int EPI>
__global__ __launch_bounds__(256)
void gemm_kernel(const __bf16* __restrict__ A, long long sA, int lda,
                 const __bf16* __restrict__ BT, long long sB, int ldb,
                 void* __restrict__ Cv, long long sC, int ldc,
                 const float* __restrict__ bias, long long sBias,
                 int K, __bf16* __restrict__ qb, __bf16* __restrict__ kb,
                 __bf16* __restrict__ vt, int zoff)
{
  constexpr int WM = BM / 2, WN = BN / 2, FM = WM / 16, FN = WN / 16;
  constexpr int LA = (BM * BK) / 2048, LB = (BN * BK) / 2048;
  __shared__ __bf16 lA[2 * BM * BK];
  __shared__ __bf16 lB[2 * BN * BK];
  const int tid  = threadIdx.x;
  const int lane = tid & 63, wave = tid >> 6;
  const int wr = wave >> 1, wc = wave & 1;
  const int bz = blockIdx.z;
  A  += (long long)bz * sA;
  BT += (long long)bz * sB;
  if (bias) bias += (long long)bz * sBias;
  const int bm = blockIdx.x * BM, bn = blockIdx.y * BN;

  auto stage = [&](int buf, int k0) {
#pragma unroll
    for (int i = 0; i < LA; i++) {
      int t   = tid + i * 256;
      int row = t / (BK / 8);
      int kc  = (t % (BK / 8)) * 8;
      gload_lds16(A + (long long)(bm + row) * lda + (k0 + kc), lA + buf * BM * BK + t * 8);
    }
#pragma unroll
    for (int i = 0; i < LB; i++) {
      int t   = tid + i * 256;
      int row = t / (BK / 8);
      int kc  = (t % (BK / 8)) * 8;
      gload_lds16(BT + (long long)(bn + row) * ldb + (k0 + kc), lB + buf * BN * BK + t * 8);
    }
  };

  f32x4 acc[FM][FN] = {};
  const int nt = K / BK;
  stage(0, 0);

  for (int t = 0; t < nt; t++) {
    __syncthreads();                       // buf[t&1] staged; prev reads done
    if (t + 1 < nt) stage((t + 1) & 1, (t + 1) * BK);
    const __bf16* cA = lA + (t & 1) * BM * BK;
    const __bf16* cB = lB + (t & 1) * BN * BK;
#pragma unroll
    for (int kk = 0; kk < BK; kk += 32) {
      bf16x8 af[FM], bfr[FN];
      const int kof = kk + (lane >> 4) * 8;
      const int r16 = lane & 15;
#pragma unroll
      for (int i = 0; i < FM; i++)
        af[i] = *(const bf16x8*)(cA + (wr * WM + i * 16 + r16) * BK + kof);
#pragma unroll
      for (int j = 0; j < FN; j++)
        bfr[j] = *(const bf16x8*)(cB + (wc * WN + j * 16 + r16) * BK + kof);
#pragma unroll
      for (int i = 0; i < FM; i++)
#pragma unroll
        for (int j = 0; j < FN; j++)
          acc[i][j] = __builtin_amdgcn_mfma_f32_16x16x32_bf16(af[i], bfr[j], acc[i][j], 0, 0, 0);
    }
  }

#pragma unroll
  for (int i = 0; i < FM; i++) {
#pragma unroll
    for (int j = 0; j < FN; j++) {
      int row0 = bm + wr * WM + i * 16 + (lane >> 4) * 4;
      int col  = bn + wc * WN + j * 16 + (lane & 15);
      float bv = bias ? bias[col] : 0.f;
      if constexpr (EPI == 2) {
        int z = bz + zoff;
        int b = row0 >> 10, s = row0 & 1023;
        int h = col >> 6, dk = col & 63;
        long long bh = b * 8 + h;
        if (z == 2) {
          bf16x4 vv;
#pragma unroll
          for (int r = 0; r < 4; r++) vv[r] = (__bf16)(acc[i][j][r] + bv);
          *(bf16x4*)(vt + (bh << 16) + (dk << 10) + s) = vv;
        } else {
          __bf16* dst = (z == 0) ? qb : kb;
          float sc = (z == 0) ? 0.125f : 1.0f;
#pragma unroll
          for (int r = 0; r < 4; r++)
            dst[(bh << 16) + ((long long)(s + r) << 6) + dk] = (__bf16)((acc[i][j][r] + bv) * sc);
        }
      } else if constexpr (EPI == 1) {
        __bf16* C = (__bf16*)Cv;
        C += (long long)bz * sC;
#pragma unroll
        for (int r = 0; r < 4; r++)
          C[(long long)(row0 + r) * ldc + col] = (__bf16)fmaxf(acc[i][j][r] + bv, 0.f);
      } else {
        float* C = (float*)Cv;
        C += (long long)bz * sC;
#pragma unroll
        for (int r = 0; r < 4; r++)
          C[(long long)(row0 + r) * ldc + col] = acc[i][j][r] + bv;
      }
    }
  }
}

// ---------------------------------------------------------------------------
// Flash attention: per block one (bh, 64-row q-tile); 4 waves, 16 q-rows each.
// qb,kb: [bh][1024][64] bf16 (q pre-scaled by 1/8); vt: [bh][64][1024] bf16.
// KV tiles of 128 double-buffered in XOR-swizzled LDS; online softmax; P via
// per-wave swizzled LDS; output merged-head bf16 [4096][512].
template<int CAUSAL>
__global__ __launch_bounds__(256)
void flash_kernel(const __bf16* __restrict__ qb, const __bf16* __restrict__ kb,
                  const __bf16* __restrict__ vt, const int* __restrict__ smask,
                  __bf16* __restrict__ Ob)
{
  __shared__ __bf16 lK[2 * 128 * 64];   // swizzled [128 k][64 d] x2
  __shared__ __bf16 lV[2 * 64 * 128];   // swizzled [64 d][128 k] x2
  __shared__ __bf16 lP[4][16 * 128];    // per-wave swizzled [16 q][128 k]
  const int bh = blockIdx.y;
  const int b = bh >> 3, h = bh & 7;
  const int q0 = blockIdx.x * 64;
  const int tid = threadIdx.x, lane = tid & 63, w = tid >> 6;
  const char* kh = (const char*)(kb + ((long long)bh << 16));
  const char* vh = (const char*)(vt + ((long long)bh << 16));

  auto stageKV = [&](int buf, int t) {
    int k0 = t * 128;
#pragma unroll
    for (int i = 0; i < 4; i++) {  // K tile: 128 rows x 128B
      int c = tid + i * 256;
      int row = c >> 3, cb = (c & 7) << 4;
      int cl = cb ^ ((row & 7) << 4);
      gload_lds16(kh + (long long)(k0 + row) * 128 + cl, (char*)lK + buf * 16384 + c * 16);
    }
#pragma unroll
    for (int i = 0; i < 4; i++) {  // V^T tile: 64 rows x 256B slice
      int c = tid + i * 256;
      int row = c >> 4, cb = (c & 15) << 4;
      int cl = cb ^ ((row & 7) << 4);
      gload_lds16(vh + (long long)row * 2048 + (long long)k0 * 2 + cl, (char*)lV + buf * 16384 + c * 16);
    }
  };

  // Q fragments (A-operand)
  bf16x8 qa[2];
  {
    const __bf16* qrow = qb + ((long long)bh << 16)
                       + (long long)(q0 + w * 16 + (lane & 15)) * 64 + (lane >> 4) * 8;
    qa[0] = *(const bf16x8*)(qrow);
    qa[1] = *(const bf16x8*)(qrow + 32);
  }
  f32x4 oacc[4] = {};
  float m[4], l[4];
#pragma unroll
  for (int r = 0; r < 4; r++) { m[r] = -3e38f; l[r] = 0.f; }

  const int nt = CAUSAL ? (blockIdx.x / 2 + 1) : 8;
  char* lPw = (char*)lP + w * 4096;
  stageKV(0, 0);

  for (int t = 0; t < nt; t++) {
    const int k0 = t * 128;
    __syncthreads();                       // buf[t&1] staged; prev reads done
    if (t + 1 < nt) stageKV((t + 1) & 1, t + 1);
    char* cK = (char*)lK + (t & 1) * 16384;
    char* cV = (char*)lV + (t & 1) * 16384;

    // ---- S = Q @ K^T ----
    f32x4 sf[8];
#pragma unroll
    for (int f = 0; f < 8; f++) {
      int row = f * 16 + (lane & 15);
      f32x4 s = {};
#pragma unroll
      for (int ks = 0; ks < 2; ks++) {
        int cb = ks * 64 + (lane >> 4) * 16;
        bf16x8 kf = *(const bf16x8*)(cK + row * 128 + (cb ^ ((row & 7) << 4)));
        s = __builtin_amdgcn_mfma_f32_16x16x32_bf16(qa[ks], kf, s, 0, 0, 0);
      }
      sf[f] = s;
    }

    // ---- masking ----
    if (!CAUSAL) {
#pragma unroll
      for (int f = 0; f < 8; f++) {
        if (smask[b * 1024 + k0 + f * 16 + (lane & 15)] == 0) {
#pragma unroll
          for (int r = 0; r < 4; r++) sf[f][r] = -1e30f;
        }
      }
    } else if (t == nt - 1) {
#pragma unroll
      for (int f = 0; f < 8; f++) {
        int kc = k0 + f * 16 + (lane & 15);
#pragma unroll
        for (int r = 0; r < 4; r++) {
          int qr = q0 + w * 16 + (lane >> 4) * 4 + r;
          if (kc > qr) sf[f][r] = -1e30f;
        }
      }
    }

    // ---- online softmax ----
    float mt[4], mn[4], cr[4], rs[4];
#pragma unroll
    for (int r = 0; r < 4; r++) {
      float v = sf[0][r];
#pragma unroll
      for (int f = 1; f < 8; f++) v = fmaxf(v, sf[f][r]);
      mt[r] = v;
    }
#pragma unroll
    for (int o = 1; o < 16; o <<= 1)
#pragma unroll
      for (int r = 0; r < 4; r++) mt[r] = fmaxf(mt[r], __shfl_xor(mt[r], o));
#pragma unroll
    for (int r = 0; r < 4; r++) {
      mn[r] = fmaxf(m[r], mt[r]);
      cr[r] = __expf(m[r] - mn[r]);
      m[r]  = mn[r];
      rs[r] = 0.f;
    }
#pragma unroll
    for (int f = 0; f < 8; f++)
#pragma unroll
      for (int r = 0; r < 4; r++) {
        float p = __expf(sf[f][r] - mn[r]);
        sf[f][r] = p;
        rs[r] += p;
      }
#pragma unroll
    for (int o = 1; o < 16; o <<= 1)
#pragma unroll
      for (int r = 0; r < 4; r++) rs[r] += __shfl_xor(rs[r], o);
#pragma unroll
    for (int r = 0; r < 4; r++) l[r] = l[r] * cr[r] + rs[r];
#pragma unroll
    for (int d = 0; d < 4; d++)
#pragma unroll
      for (int r = 0; r < 4; r++) oacc[d][r] *= cr[r];

    // ---- write P to per-wave swizzled LDS ----
#pragma unroll
    for (int f = 0; f < 8; f++) {
      int colB = f * 32 + (lane & 15) * 2;
#pragma unroll
      for (int r = 0; r < 4; r++) {
        int row = (lane >> 4) * 4 + r;
        *(__bf16*)(lPw + row * 256 + (colB ^ ((row & 7) << 4))) = (__bf16)sf[f][r];
      }
    }
    asm volatile("s_waitcnt lgkmcnt(0)" ::: "memory");

    // ---- O += P @ V ----
#pragma unroll
    for (int ks = 0; ks < 4; ks++) {
      int prow = lane & 15;
      int cb = ks * 64 + (lane >> 4) * 16;
      bf16x8 pa = *(const bf16x8*)(lPw + prow * 256 + (cb ^ ((prow & 7) << 4)));
#pragma unroll
      for (int d = 0; d < 4; d++) {
        int vrow = d * 16 + (lane & 15);
        bf16x8 vf = *(const bf16x8*)(cV + vrow * 256 + (cb ^ ((vrow & 7) << 4)));
        oacc[d] = __builtin_amdgcn_mfma_f32_16x16x32_bf16(pa, vf, oacc[d], 0, 0, 0);
      }
    }
  }

  // ---- epilogue ----
  float inv[4];
#pragma unroll
  for (int r = 0; r < 4; r++) inv[r] = 1.f / l[r];
#pragma unroll
  for (int d = 0; d < 4; d++)
#pragma unroll
    for (int r = 0; r < 4; r++) {
      long long row = b * 1024 + q0 + w * 16 + (lane >> 4) * 4 + r;
      Ob[row * 512 + h * 64 + d * 16 + (lane & 15)] = (__bf16)(oacc[d][r] * inv[r]);
    }
}

// ---------------------------------------------------------------------------
// W[K,N] fp32 -> WT[N,K] bf16 (batched over z). Block (32,8), grid (N/32,K/32,z).
__global__ void transpose_w_kernel(const float* __restrict__ W, __bf16* __restrict__ WT,
                                   int K, int N)
{
  __shared__ float t[32][33];
  long long mz = (long long)blockIdx.z * K * N;
  W += mz; WT += mz;
  int n0 = blockIdx.x * 32, k0 = blockIdx.y * 32;
  int tx = threadIdx.x, ty = threadIdx.y;
#pragma unroll
  for (int i = 0; i < 32; i += 8)
    t[ty + i][tx] = W[(long long)(k0 + ty + i) * N + (n0 + tx)];
  __syncthreads();
#pragma unroll
  for (int i = 0; i < 32; i += 8)
    WT[(long long)(n0 + ty + i) * K + (k0 + tx)] = (__bf16)t[tx][ty + i];
}

// x = emb[idx] + positional encoding; writes fp32 + bf16. Grid 4096, block 128.
__global__ void embed_kernel(const float* __restrict__ emb, const int* __restrict__ idx,
                             float* __restrict__ X, __bf16* __restrict__ Xb)
{
  int row = blockIdx.x;
  int s   = row & 1023;
  int tok = idx[row];
  int d0  = threadIdx.x * 4;
  float4 e = *(const float4*)(emb + (long long)tok * 512 + d0);
  const float* ep = (const float*)&e;
  float o[4];
#pragma unroll
  for (int j = 0; j < 4; j++) {
    int d = d0 + j;
    float div = expf((float)(d & ~1) * (-9.210340371976184f / 512.f));
    float ang = (float)s * div;
    float pe  = (d & 1) ? cosf(ang) : sinf(ang);
    o[j] = ep[j] + pe;
  }
  *(float4*)(X + (long long)row * 512 + d0) = *(float4*)o;
  bf16x4 ob;
#pragma unroll
  for (int j = 0; j < 4; j++) ob[j] = (__bf16)o[j];
  *(bf16x4*)(Xb + (long long)row * 512 + d0) = ob;
}

// LayerNorm(Xin + Rin) * g + b. One wave per 512-row. Writes fp32 (opt) + bf16.
__global__ void ln_kernel(const float* __restrict__ Xin, const float* __restrict__ Rin,
                          const float* __restrict__ g, const float* __restrict__ b,
                          float* __restrict__ Xout, __bf16* __restrict__ Xbout)
{
  int row = blockIdx.x, lane = threadIdx.x;  // 64
  long long base = (long long)row * 512 + lane * 8;
  float x[8];
  *(float4*)x       = *(const float4*)(Xin + base);
  *(float4*)(x + 4) = *(const float4*)(Xin + base + 4);
  if (Rin) {
    float4 r0 = *(const float4*)(Rin + base);
    float4 r1 = *(const float4*)(Rin + base + 4);
    x[0] += r0.x; x[1] += r0.y; x[2] += r0.z; x[3] += r0.w;
    x[4] += r1.x; x[5] += r1.y; x[6] += r1.z; x[7] += r1.w;
  }
  float s = 0.f;
#pragma unroll
  for (int i = 0; i < 8; i++) s += x[i];
#pragma unroll
  for (int o = 32; o > 0; o >>= 1) s += __shfl_xor(s, o);
  float mean = s * (1.f / 512.f);
  float v = 0.f;
#pragma unroll
  for (int i = 0; i < 8; i++) { x[i] -= mean; v += x[i] * x[i]; }
#pragma unroll
  for (int o = 32; o > 0; o >>= 1) v += __shfl_xor(v, o);
  float inv = rsqrtf(v * (1.f / 512.f) + 1e-5f);
  int d0 = lane * 8;
  float gg[8], bb[8];
  *(float4*)gg       = *(const float4*)(g + d0);
  *(float4*)(gg + 4) = *(const float4*)(g + d0 + 4);
  *(float4*)bb       = *(const float4*)(b + d0);
  *(float4*)(bb + 4) = *(const float4*)(b + d0 + 4);
  float y[8]; bf16x8 yb;
#pragma unroll
  for (int i = 0; i < 8; i++) {
    y[i] = x[i] * inv * gg[i] + bb[i];
    yb[i] = (__bf16)y[i];
  }
  if (Xout) {
    *(float4*)(Xout + base)     = *(float4*)y;
    *(float4*)(Xout + base + 4) = *(float4*)(y + 4);
  }
  *(bf16x8*)(Xbout + base) = yb;
}

// ---------------------------------------------------------------------------
extern "C" void kernel_launch(void* const* d_in, const int* in_sizes, int n_in,
                              void* d_out, int out_size, void* d_ws, size_t ws_size,
                              hipStream_t stream)
{
  (void)in_sizes; (void)n_in; (void)out_size; (void)ws_size;
  const float* src_emb    = (const float*)d_in[0];
  const float* tgt_emb    = (const float*)d_in[1];
  const float* enc_attn_w = (const float*)d_in[2];
  const float* enc_attn_b = (const float*)d_in[3];
  const float* enc_ffn_w1 = (const float*)d_in[4];
  const float* enc_ffn_b1 = (const float*)d_in[5];
  const float* enc_ffn_w2 = (const float*)d_in[6];
  const float* enc_ffn_b2 = (const float*)d_in[7];
  const float* enc_ln_g   = (const float*)d_in[8];
  const float* enc_ln_b   = (const float*)d_in[9];
  const float* enc_fg     = (const float*)d_in[10];
  const float* enc_fb     = (const float*)d_in[11];
  const float* dec_self_w = (const float*)d_in[12];
  const float* dec_self_b = (const float*)d_in[13];
  const float* dec_src_w  = (const float*)d_in[14];
  const float* dec_src_b  = (const float*)d_in[15];
  const float* dec_ffn_w1 = (const float*)d_in[16];
  const float* dec_ffn_b1 = (const float*)d_in[17];
  const float* dec_ffn_w2 = (const float*)d_in[18];
  const float* dec_ffn_b2 = (const float*)d_in[19];
  const float* dec_ln_g   = (const float*)d_in[20];
  const float* dec_ln_b   = (const float*)d_in[21];
  const float* dec_fg     = (const float*)d_in[22];
  const float* dec_fb     = (const float*)d_in[23];
  const float* gen_w      = (const float*)d_in[24];
  const float* gen_b      = (const float*)d_in[25];
  const int*   src        = (const int*)d_in[26];
  const int*   tgt        = (const int*)d_in[27];
  const int*   src_mask   = (const int*)d_in[28];

  float* out = (float*)d_out;

  // ---- workspace (~130 MB) ----
  char* wp = (char*)d_ws;
  auto alloc = [&](size_t bytes) { void* p = (void*)wp; wp += (bytes + 255) & ~(size_t)255; return p; };
  // encoder-only transposed weights first: GENT aliases them after encoder.
  __bf16* TWea = (__bf16*)alloc(24ull * 262144 * 2);    // enc attn  [6][4][512][512]^T
  __bf16* TWe1 = (__bf16*)alloc(6ull * 1048576 * 2);    // enc ffn1  [6][2048][512]
  __bf16* TWe2 = (__bf16*)alloc(6ull * 1048576 * 2);    // enc ffn2  [6][512][2048]
  __bf16* TWds = (__bf16*)alloc(24ull * 262144 * 2);    // dec self
  __bf16* TWdx = (__bf16*)alloc(24ull * 262144 * 2);    // dec src
  __bf16* TWd1 = (__bf16*)alloc(6ull * 1048576 * 2);    // dec ffn1
  __bf16* TWd2 = (__bf16*)alloc(6ull * 1048576 * 2);    // dec ffn2
  float*  X    = (float*) alloc(4096ull * 512 * 4);
  __bf16* Xb   = (__bf16*)alloc(4096ull * 512 * 2);
  __bf16* MEMb = (__bf16*)alloc(4096ull * 512 * 2);
  float*  R    = (float*) alloc(4096ull * 512 * 4);
  __bf16* qb   = (__bf16*)alloc(32ull * 1024 * 64 * 2); // } union with Fb
  __bf16* kb   = (__bf16*)alloc(32ull * 1024 * 64 * 2);
  __bf16* vt   = (__bf16*)alloc(32ull * 1024 * 64 * 2);
  __bf16* Ob   = (__bf16*)alloc(4096ull * 512 * 2);
  __bf16* Fb   = qb;                                    // ffn hidden bf16 [4096][2048]
  __bf16* GENT = TWea;                                  // gen_w^T, after encoder

  // ---- bulk weight transposes (8 launches) ----
  transpose_w_kernel<<<dim3(16, 16, 24), dim3(32, 8), 0, stream>>>(enc_attn_w, TWea, 512, 512);
  transpose_w_kernel<<<dim3(64, 16, 6),  dim3(32, 8), 0, stream>>>(enc_ffn_w1, TWe1, 512, 2048);
  transpose_w_kernel<<<dim3(16, 64, 6),  dim3(32, 8), 0, stream>>>(enc_ffn_w2, TWe2, 2048, 512);
  transpose_w_kernel<<<dim3(16, 16, 24), dim3(32, 8), 0, stream>>>(dec_self_w, TWds, 512, 512);
  transpose_w_kernel<<<dim3(16, 16, 24), dim3(32, 8), 0, stream>>>(dec_src_w,  TWdx, 512, 512);
  transpose_w_kernel<<<dim3(64, 16, 6),  dim3(32, 8), 0, stream>>>(dec_ffn_w1, TWd1, 512, 2048);
  transpose_w_kernel<<<dim3(16, 64, 6),  dim3(32, 8), 0, stream>>>(dec_ffn_w2, TWd2, 2048, 512);

  // attention: wt = 4 transposed weights for this layer; writes R.
  auto attention = [&](const __bf16* wt, const float* bptr, int causal,
                       const __bf16* Aq, const __bf16* Akv) {
    if (Aq == Akv) {
      gemm_kernel<128, 128, 64, 2><<<dim3(32, 4, 3), 256, 0, stream>>>(
          Aq, 0, 512, wt, 262144, 512, nullptr, 0, 0, bptr, 512, 512, qb, kb, vt, 0);
    } else {
      gemm_kernel<128, 64, 64, 2><<<dim3(32, 8, 1), 256, 0, stream>>>(
          Aq, 0, 512, wt, 0, 512, nullptr, 0, 0, bptr, 0, 512, qb, kb, vt, 0);
      gemm_kernel<128, 64, 64, 2><<<dim3(32, 8, 2), 256, 0, stream>>>(
          Akv, 0, 512, wt + 262144, 262144, 512, nullptr, 0, 0, bptr + 512, 512, 512, qb, kb, vt, 1);
    }
    if (causal)
      flash_kernel<1><<<dim3(16, 32), 256, 0, stream>>>(qb, kb, vt, nullptr, Ob);
    else
      flash_kernel<0><<<dim3(16, 32), 256, 0, stream>>>(qb, kb, vt, src_mask, Ob);
    gemm_kernel<128, 64, 64, 0><<<dim3(32, 8, 1), 256, 0, stream>>>(
        Ob, 0, 512, wt + 3 * 262144, 0, 512, R, 0, 512, bptr + 3 * 512, 0, 512,
        nullptr, nullptr, nullptr, 0);
  };

  auto ffn = [&](const __bf16* w1t, const float* b1, const __bf16* w2t, const float* b2) {
    gemm_kernel<128, 128, 64, 1><<<dim3(32, 16, 1), 256, 0, stream>>>(
        Xb, 0, 512, w1t, 0, 512, Fb, 0, 2048, b1, 0, 512, nullptr, nullptr, nullptr, 0);
    gemm_kernel<128, 64, 64, 0><<<dim3(32, 8, 1), 256, 0, stream>>>(
        Fb, 0, 2048, w2t, 0, 2048, R, 0, 512, b2, 0, 2048, nullptr, nullptr, nullptr, 0);
  };

  // ---------------- encoder ----------------
  embed_kernel<<<4096, 128, 0, stream>>>(src_emb, src, X, Xb);
  for (int i = 0; i < 6; i++) {
    attention(TWea + (long long)i * 1048576, enc_attn_b + i * 2048, 0, Xb, Xb);
    ln_kernel<<<4096, 64, 0, stream>>>(X, R, enc_ln_g + i * 1024, enc_ln_b + i * 1024, X, Xb);
    ffn(TWe1 + (long long)i * 1048576, enc_ffn_b1 + i * 2048,
        TWe2 + (long long)i * 1048576, enc_ffn_b2 + i * 512);
    ln_kernel<<<4096, 64, 0, stream>>>(X, R, enc_ln_g + i * 1024 + 512, enc_ln_b + i * 1024 + 512, X, Xb);
  }
  ln_kernel<<<4096, 64, 0, stream>>>(X, nullptr, enc_fg, enc_fb, nullptr, MEMb);

  // gen_w^T into the dead encoder-weight region (safe: encoder weights unused now)
  transpose_w_kernel<<<dim3(1000, 16, 1), dim3(32, 8), 0, stream>>>(gen_w, GENT, 512, 32000);

  // ---------------- decoder ----------------
  embed_kernel<<<4096, 128, 0, stream>>>(tgt_emb, tgt, X, Xb);
  for (int i = 0; i < 6; i++) {
    attention(TWds + (long long)i * 1048576, dec_self_b + i * 2048, 1, Xb, Xb);
    ln_kernel<<<4096, 64, 0, stream>>>(X, R, dec_ln_g + i * 1536, dec_ln_b + i * 1536, X, Xb);

    attention(TWdx + (long long)i * 1048576, dec_src_b + i * 2048, 0, Xb, MEMb);
    ln_kernel<<<4096, 64, 0, stream>>>(X, R, dec_ln_g + i * 1536 + 512, dec_ln_b + i * 1536 + 512, X, Xb);

    ffn(TWd1 + (long long)i * 1048576, dec_ffn_b1 + i * 2048,
        TWd2 + (long long)i * 1048576, dec_ffn_b2 + i * 512);
    ln_kernel<<<4096, 64, 0, stream>>>(X, R, dec_ln_g + i * 1536 + 1024, dec_ln_b + i * 1536 + 1024, X, Xb);
  }
  ln_kernel<<<4096, 64, 0, stream>>>(X, nullptr, dec_fg, dec_fb, nullptr, Xb);

  // ---------------- generator ----------------
  gemm_kernel<128, 128, 64, 0><<<dim3(32, 250, 1), 256, 0, stream>>>(
      Xb, 0, 512, GENT, 0, 512, out, 0, 32000, gen_b, 0, 512, nullptr, nullptr, nullptr, 0);
}

// Round 4
// 2442.777 us; speedup vs baseline: 1.8751x; 1.0097x over previous
//
#include <hip/hip_runtime.h>

// ---------------------------------------------------------------------------
// Transformer (enc-dec, D=512, H=8, N=6, DFF=2048, B=4, S=T=1024, V=32000)
// bf16 MFMA GEMMs, fp32 accum. 8-phase 256^2 kernel (T2 swizzle + counted
// vmcnt + setprio) for generator/FFN1; 2-phase 128-tile kernel elsewhere;
// fused flash attention; fp32 residual/LN.
// ---------------------------------------------------------------------------

typedef __bf16 bf16x8 __attribute__((ext_vector_type(8)));
typedef __bf16 bf16x4 __attribute__((ext_vector_type(4)));
typedef float  f32x4  __attribute__((ext_vector_type(4)));

__device__ __forceinline__ void gload_lds16(const void* g, void* l) {
  __builtin_amdgcn_global_load_lds((__attribute__((address_space(1))) void*)g,
                                   (__attribute__((address_space(3))) void*)l,
                                   16, 0, 0);
}

__device__ __forceinline__ void hard_barrier() {
  asm volatile("" ::: "memory");
  __builtin_amdgcn_sched_barrier(0);
  __builtin_amdgcn_s_barrier();
  __builtin_amdgcn_sched_barrier(0);
  asm volatile("" ::: "memory");
}

// ---------------------------------------------------------------------------
// 8-phase 256x256 GEMM: C = A[M,K] @ BT[N,K]^T + bias. 512 thr, 8 waves (2x4).
// 2 LDS slots x (A[256][64] + B[256][64]) bf16, XOR-swizzled ((row&7)<<4).
// Counted vmcnt(8): slot for K-tile t+2 staged after release of tile t.
// EPI 0: C fp32 + bias.  EPI 1: C bf16 + bias + ReLU.
template<int EPI>
__global__ __launch_bounds__(512, 2)
void gemm256_kernel(const __bf16* __restrict__ A, int lda,
                    const __bf16* __restrict__ BT, int ldb,
                    void* __restrict__ Cv, int ldc,
                    const float* __restrict__ bias, int K)
{
  __shared__ __bf16 lds[2 * 2 * 256 * 64];   // 128 KB: slot*65536B {A,B}
  const int tid = threadIdx.x, lane = tid & 63;
  const int w = tid >> 6, wr = w >> 2, wc = w & 3;
  const int bm = blockIdx.x * 256, bn = blockIdx.y * 256;

  auto stage = [&](int slot, int kt) {
    const long long k0b = (long long)kt * 128;  // byte offset in K
    const char* Ag = (const char*)A;
    const char* Bg = (const char*)BT;
    char* ldsb = (char*)lds + slot * 65536;
#pragma unroll
    for (int i = 0; i < 4; i++) {
      int c = tid + i * 512;                    // 0..2047
      int row = c >> 3, cb = (c & 7) << 4;
      int src = cb ^ ((row & 7) << 4);          // pre-swizzled source (rule #21)
      gload_lds16(Ag + ((long long)(bm + row) * lda) * 2 + k0b + src, ldsb + c * 16);
    }
#pragma unroll
    for (int i = 0; i < 4; i++) {
      int c = tid + i * 512;
      int row = c >> 3, cb = (c & 7) << 4;
      int src = cb ^ ((row & 7) << 4);
      gload_lds16(Bg + ((long long)(bn + row) * ldb) * 2 + k0b + src, ldsb + 32768 + c * 16);
    }
  };

  f32x4 acc[8][4] = {};
  const int NT = K / 64;                        // >= 2 for all call sites

  stage(0, 0);
  stage(1, 1);
  asm volatile("s_waitcnt vmcnt(8)" ::: "memory");  // slot0 resident
  __builtin_amdgcn_sched_barrier(0);
  __builtin_amdgcn_s_barrier();
  __builtin_amdgcn_sched_barrier(0);

  for (int kt = 0; kt < NT; kt++) {
    const char* sA = (const char*)lds + (kt & 1) * 65536;
    const char* sB = sA + 32768;
#pragma unroll
    for (int q = 0; q < 4; q++) {               // 4 quadrant phases
      const int qr = q >> 1, qc = q & 1;
      bf16x8 af[4][2], bf[2][2];
#pragma unroll
      for (int i = 0; i < 4; i++) {
        int row = wr * 128 + qr * 64 + i * 16 + (lane & 15);
#pragma unroll
        for (int kk = 0; kk < 2; kk++) {
          int g = kk * 64 + (lane >> 4) * 16;
          af[i][kk] = *(const bf16x8*)(sA + row * 128 + (g ^ ((row & 7) << 4)));
        }
      }
#pragma unroll
      for (int j = 0; j < 2; j++) {
        int row = wc * 64 + qc * 32 + j * 16 + (lane & 15);
#pragma unroll
        for (int kk = 0; kk < 2; kk++) {
          int g = kk * 64 + (lane >> 4) * 16;
          bf[j][kk] = *(const bf16x8*)(sB + row * 128 + (g ^ ((row & 7) << 4)));
        }
      }
      __builtin_amdgcn_s_setprio(1);
#pragma unroll
      for (int kk = 0; kk < 2; kk++)
#pragma unroll
        for (int i = 0; i < 4; i++)
#pragma unroll
          for (int j = 0; j < 2; j++)
            acc[qr * 4 + i][qc * 2 + j] = __builtin_amdgcn_mfma_f32_16x16x32_bf16(
                af[i][kk], bf[j][kk], acc[qr * 4 + i][qc * 2 + j], 0, 0, 0);
      __builtin_amdgcn_s_setprio(0);
    }
    hard_barrier();                             // all waves done reading slot kt&1
    if (kt + 2 < NT) {
      stage(kt & 1, kt + 2);                    // refill released slot
      asm volatile("s_waitcnt vmcnt(8)" ::: "memory");  // K-tile kt+1 resident
    } else {
      asm volatile("s_waitcnt vmcnt(0)" ::: "memory");
    }
    __builtin_amdgcn_sched_barrier(0);
    __builtin_amdgcn_s_barrier();
    __builtin_amdgcn_sched_barrier(0);
  }

#pragma unroll
  for (int mi = 0; mi < 8; mi++) {
#pragma unroll
    for (int ni = 0; ni < 4; ni++) {
      int row0 = bm + wr * 128 + mi * 16 + (lane >> 4) * 4;
      int col  = bn + wc * 64 + ni * 16 + (lane & 15);
      float bv = bias ? bias[col] : 0.f;
      if constexpr (EPI == 1) {
        __bf16* C = (__bf16*)Cv;
#pragma unroll
        for (int r = 0; r < 4; r++)
          C[(long long)(row0 + r) * ldc + col] = (__bf16)fmaxf(acc[mi][ni][r] + bv, 0.f);
      } else {
        float* C = (float*)Cv;
#pragma unroll
        for (int r = 0; r < 4; r++)
          C[(long long)(row0 + r) * ldc + col] = acc[mi][ni][r] + bv;
      }
    }
  }
}

// ---------------------------------------------------------------------------
// 2-phase GEMM: C = A[M,K] @ BT[N,K]^T + bias. 256 thr, 4 waves.
// EPI 0: C fp32.  EPI 2: route cols to qb/kb/vt head layouts (z = zoff+col>>9).
template<int BM, int BN, int BK, int EPI>
__global__ __launch_bounds__(256)
void gemm_kernel(const __bf16* __restrict__ A, int lda,
                 const __bf16* __restrict__ BT, int ldb,
                 void* __restrict__ Cv, int ldc,
                 const float* __restrict__ bias, int K,
                 __bf16* __restrict__ qb, __bf16* __restrict__ kb,
                 __bf16* __restrict__ vt, int zoff)
{
  constexpr int WM = BM / 2, WN = BN / 2, FM = WM / 16, FN = WN / 16;
  constexpr int LA = (BM * BK) / 2048, LB = (BN * BK) / 2048;
  __shared__ __bf16 lA[2 * BM * BK];
  __shared__ __bf16 lB[2 * BN * BK];
  const int tid  = threadIdx.x;
  const int lane = tid & 63, wave = tid >> 6;
  const int wr = wave >> 1, wc = wave & 1;
  const int bm = blockIdx.x * BM, bn = blockIdx.y * BN;

  auto stage = [&](int buf, int k0) {
#pragma unroll
    for (int i = 0; i < LA; i++) {
      int t   = tid + i * 256;
      int row = t / (BK / 8);
      int kc  = (t % (BK / 8)) * 8;
      gload_lds16(A + (long long)(bm + row) * lda + (k0 + kc), lA + buf * BM * BK + t * 8);
    }
#pragma unroll
    for (int i = 0; i < LB; i++) {
      int t   = tid + i * 256;
      int row = t / (BK / 8);
      int kc  = (t % (BK / 8)) * 8;
      gload_lds16(BT + (long long)(bn + row) * ldb + (k0 + kc), lB + buf * BN * BK + t * 8);
    }
  };

  f32x4 acc[FM][FN] = {};
  const int nt = K / BK;
  stage(0, 0);

  for (int t = 0; t < nt; t++) {
    __syncthreads();
    if (t + 1 < nt) stage((t + 1) & 1, (t + 1) * BK);
    const __bf16* cA = lA + (t & 1) * BM * BK;
    const __bf16* cB = lB + (t & 1) * BN * BK;
#pragma unroll
    for (int kk = 0; kk < BK; kk += 32) {
      bf16x8 af[FM], bfr[FN];
      const int kof = kk + (lane >> 4) * 8;
      const int r16 = lane & 15;
#pragma unroll
      for (int i = 0; i < FM; i++)
        af[i] = *(const bf16x8*)(cA + (wr * WM + i * 16 + r16) * BK + kof);
#pragma unroll
      for (int j = 0; j < FN; j++)
        bfr[j] = *(const bf16x8*)(cB + (wc * WN + j * 16 + r16) * BK + kof);
#pragma unroll
      for (int i = 0; i < FM; i++)
#pragma unroll
        for (int j = 0; j < FN; j++)
          acc[i][j] = __builtin_amdgcn_mfma_f32_16x16x32_bf16(af[i], bfr[j], acc[i][j], 0, 0, 0);
    }
  }

#pragma unroll
  for (int i = 0; i < FM; i++) {
#pragma unroll
    for (int j = 0; j < FN; j++) {
      int row0 = bm + wr * WM + i * 16 + (lane >> 4) * 4;
      int col  = bn + wc * WN + j * 16 + (lane & 15);
      float bv = bias ? bias[col] : 0.f;
      if constexpr (EPI == 2) {
        int z = zoff + (col >> 9);
        int cw = col & 511;
        int b = row0 >> 10, s = row0 & 1023;
        int h = cw >> 6, dk = cw & 63;
        long long bh = b * 8 + h;
        if (z == 2) {
          bf16x4 vv;
#pragma unroll
          for (int r = 0; r < 4; r++) vv[r] = (__bf16)(acc[i][j][r] + bv);
          *(bf16x4*)(vt + (bh << 16) + (dk << 10) + s) = vv;
        } else {
          __bf16* dst = (z == 0) ? qb : kb;
          float sc = (z == 0) ? 0.125f : 1.0f;
#pragma unroll
          for (int r = 0; r < 4; r++)
            dst[(bh << 16) + ((long long)(s + r) << 6) + dk] = (__bf16)((acc[i][j][r] + bv) * sc);
        }
      } else {
        float* C = (float*)Cv;
#pragma unroll
        for (int r = 0; r < 4; r++)
          C[(long long)(row0 + r) * ldc + col] = acc[i][j][r] + bv;
      }
    }
  }
}

// ---------------------------------------------------------------------------
// Flash attention (unchanged from r2/r3): per block one (bh, 64-row q-tile).
template<int CAUSAL>
__global__ __launch_bounds__(256)
void flash_kernel(const __bf16* __restrict__ qb, const __bf16* __restrict__ kb,
                  const __bf16* __restrict__ vt, const int* __restrict__ smask,
                  __bf16* __restrict__ Ob)
{
  __shared__ __bf16 lK[2 * 128 * 64];
  __shared__ __bf16 lV[2 * 64 * 128];
  __shared__ __bf16 lP[4][16 * 128];
  const int bh = blockIdx.y;
  const int b = bh >> 3, h = bh & 7;
  const int q0 = blockIdx.x * 64;
  const int tid = threadIdx.x, lane = tid & 63, w = tid >> 6;
  const char* kh = (const char*)(kb + ((long long)bh << 16));
  const char* vh = (const char*)(vt + ((long long)bh << 16));

  auto stageKV = [&](int buf, int t) {
    int k0 = t * 128;
#pragma unroll
    for (int i = 0; i < 4; i++) {
      int c = tid + i * 256;
      int row = c >> 3, cb = (c & 7) << 4;
      int cl = cb ^ ((row & 7) << 4);
      gload_lds16(kh + (long long)(k0 + row) * 128 + cl, (char*)lK + buf * 16384 + c * 16);
    }
#pragma unroll
    for (int i = 0; i < 4; i++) {
      int c = tid + i * 256;
      int row = c >> 4, cb = (c & 15) << 4;
      int cl = cb ^ ((row & 7) << 4);
      gload_lds16(vh + (long long)row * 2048 + (long long)k0 * 2 + cl, (char*)lV + buf * 16384 + c * 16);
    }
  };

  bf16x8 qa[2];
  {
    const __bf16* qrow = qb + ((long long)bh << 16)
                       + (long long)(q0 + w * 16 + (lane & 15)) * 64 + (lane >> 4) * 8;
    qa[0] = *(const bf16x8*)(qrow);
    qa[1] = *(const bf16x8*)(qrow + 32);
  }
  f32x4 oacc[4] = {};
  float m[4], l[4];
#pragma unroll
  for (int r = 0; r < 4; r++) { m[r] = -3e38f; l[r] = 0.f; }

  const int nt = CAUSAL ? (blockIdx.x / 2 + 1) : 8;
  char* lPw = (char*)lP + w * 4096;
  stageKV(0, 0);

  for (int t = 0; t < nt; t++) {
    const int k0 = t * 128;
    __syncthreads();
    if (t + 1 < nt) stageKV((t + 1) & 1, t + 1);
    char* cK = (char*)lK + (t & 1) * 16384;
    char* cV = (char*)lV + (t & 1) * 16384;

    f32x4 sf[8];
#pragma unroll
    for (int f = 0; f < 8; f++) {
      int row = f * 16 + (lane & 15);
      f32x4 s = {};
#pragma unroll
      for (int ks = 0; ks < 2; ks++) {
        int cb = ks * 64 + (lane >> 4) * 16;
        bf16x8 kf = *(const bf16x8*)(cK + row * 128 + (cb ^ ((row & 7) << 4)));
        s = __builtin_amdgcn_mfma_f32_16x16x32_bf16(qa[ks], kf, s, 0, 0, 0);
      }
      sf[f] = s;
    }

    if (!CAUSAL) {
#pragma unroll
      for (int f = 0; f < 8; f++) {
        if (smask[b * 1024 + k0 + f * 16 + (lane & 15)] == 0) {
#pragma unroll
          for (int r = 0; r < 4; r++) sf[f][r] = -1e30f;
        }
      }
    } else if (t == nt - 1) {
#pragma unroll
      for (int f = 0; f < 8; f++) {
        int kc = k0 + f * 16 + (lane & 15);
#pragma unroll
        for (int r = 0; r < 4; r++) {
          int qr = q0 + w * 16 + (lane >> 4) * 4 + r;
          if (kc > qr) sf[f][r] = -1e30f;
        }
      }
    }

    float mt[4], mn[4], cr[4], rs[4];
#pragma unroll
    for (int r = 0; r < 4; r++) {
      float v = sf[0][r];
#pragma unroll
      for (int f = 1; f < 8; f++) v = fmaxf(v, sf[f][r]);
      mt[r] = v;
    }
#pragma unroll
    for (int o = 1; o < 16; o <<= 1)
#pragma unroll
      for (int r = 0; r < 4; r++) mt[r] = fmaxf(mt[r], __shfl_xor(mt[r], o));
#pragma unroll
    for (int r = 0; r < 4; r++) {
      mn[r] = fmaxf(m[r], mt[r]);
      cr[r] = __expf(m[r] - mn[r]);
      m[r]  = mn[r];
      rs[r] = 0.f;
    }
#pragma unroll
    for (int f = 0; f < 8; f++)
#pragma unroll
      for (int r = 0; r < 4; r++) {
        float p = __expf(sf[f][r] - mn[r]);
        sf[f][r] = p;
        rs[r] += p;
      }
#pragma unroll
    for (int o = 1; o < 16; o <<= 1)
#pragma unroll
      for (int r = 0; r < 4; r++) rs[r] += __shfl_xor(rs[r], o);
#pragma unroll
    for (int r = 0; r < 4; r++) l[r] = l[r] * cr[r] + rs[r];
#pragma unroll
    for (int d = 0; d < 4; d++)
#pragma unroll
      for (int r = 0; r < 4; r++) oacc[d][r] *= cr[r];

#pragma unroll
    for (int f = 0; f < 8; f++) {
      int colB = f * 32 + (lane & 15) * 2;
#pragma unroll
      for (int r = 0; r < 4; r++) {
        int row = (lane >> 4) * 4 + r;
        *(__bf16*)(lPw + row * 256 + (colB ^ ((row & 7) << 4))) = (__bf16)sf[f][r];
      }
    }
    asm volatile("s_waitcnt lgkmcnt(0)" ::: "memory");

#pragma unroll
    for (int ks = 0; ks < 4; ks++) {
      int prow = lane & 15;
      int cb = ks * 64 + (lane >> 4) * 16;
      bf16x8 pa = *(const bf16x8*)(lPw + prow * 256 + (cb ^ ((prow & 7) << 4)));
#pragma unroll
      for (int d = 0; d < 4; d++) {
        int vrow = d * 16 + (lane & 15);
        bf16x8 vf = *(const bf16x8*)(cV + vrow * 256 + (cb ^ ((vrow & 7) << 4)));
        oacc[d] = __builtin_amdgcn_mfma_f32_16x16x32_bf16(pa, vf, oacc[d], 0, 0, 0);
      }
    }
  }

  float inv[4];
#pragma unroll
  for (int r = 0; r < 4; r++) inv[r] = 1.f / l[r];
#pragma unroll
  for (int d = 0; d < 4; d++)
#pragma unroll
    for (int r = 0; r < 4; r++) {
      long long row = b * 1024 + q0 + w * 16 + (lane >> 4) * 4 + r;
      Ob[row * 512 + h * 64 + d * 16 + (lane & 15)] = (__bf16)(oacc[d][r] * inv[r]);
    }
}

// ---------------------------------------------------------------------------
__global__ void transpose_w_kernel(const float* __restrict__ W, __bf16* __restrict__ WT,
                                   int K, int N)
{
  __shared__ float t[32][33];
  long long mz = (long long)blockIdx.z * K * N;
  W += mz; WT += mz;
  int n0 = blockIdx.x * 32, k0 = blockIdx.y * 32;
  int tx = threadIdx.x, ty = threadIdx.y;
#pragma unroll
  for (int i = 0; i < 32; i += 8)
    t[ty + i][tx] = W[(long long)(k0 + ty + i) * N + (n0 + tx)];
  __syncthreads();
#pragma unroll
  for (int i = 0; i < 32; i += 8)
    WT[(long long)(n0 + ty + i) * K + (k0 + tx)] = (__bf16)t[tx][ty + i];
}

__global__ void embed_kernel(const float* __restrict__ emb, const int* __restrict__ idx,
                             float* __restrict__ X, __bf16* __restrict__ Xb)
{
  int row = blockIdx.x;
  int s   = row & 1023;
  int tok = idx[row];
  int d0  = threadIdx.x * 4;
  float4 e = *(const float4*)(emb + (long long)tok * 512 + d0);
  const float* ep = (const float*)&e;
  float o[4];
#pragma unroll
  for (int j = 0; j < 4; j++) {
    int d = d0 + j;
    float div = expf((float)(d & ~1) * (-9.210340371976184f / 512.f));
    float ang = (float)s * div;
    float pe  = (d & 1) ? cosf(ang) : sinf(ang);
    o[j] = ep[j] + pe;
  }
  *(float4*)(X + (long long)row * 512 + d0) = *(float4*)o;
  bf16x4 ob;
#pragma unroll
  for (int j = 0; j < 4; j++) ob[j] = (__bf16)o[j];
  *(bf16x4*)(Xb + (long long)row * 512 + d0) = ob;
}

__global__ void ln_kernel(const float* __restrict__ Xin, const float* __restrict__ Rin,
                          const float* __restrict__ g, const float* __restrict__ b,
                          float* __restrict__ Xout, __bf16* __restrict__ Xbout)
{
  int row = blockIdx.x, lane = threadIdx.x;
  long long base = (long long)row * 512 + lane * 8;
  float x[8];
  *(float4*)x       = *(const float4*)(Xin + base);
  *(float4*)(x + 4) = *(const float4*)(Xin + base + 4);
  if (Rin) {
    float4 r0 = *(const float4*)(Rin + base);
    float4 r1 = *(const float4*)(Rin + base + 4);
    x[0] += r0.x; x[1] += r0.y; x[2] += r0.z; x[3] += r0.w;
    x[4] += r1.x; x[5] += r1.y; x[6] += r1.z; x[7] += r1.w;
  }
  float s = 0.f;
#pragma unroll
  for (int i = 0; i < 8; i++) s += x[i];
#pragma unroll
  for (int o = 32; o > 0; o >>= 1) s += __shfl_xor(s, o);
  float mean = s * (1.f / 512.f);
  float v = 0.f;
#pragma unroll
  for (int i = 0; i < 8; i++) { x[i] -= mean; v += x[i] * x[i]; }
#pragma unroll
  for (int o = 32; o > 0; o >>= 1) v += __shfl_xor(v, o);
  float inv = rsqrtf(v * (1.f / 512.f) + 1e-5f);
  int d0 = lane * 8;
  float gg[8], bb[8];
  *(float4*)gg       = *(const float4*)(g + d0);
  *(float4*)(gg + 4) = *(const float4*)(g + d0 + 4);
  *(float4*)bb       = *(const float4*)(b + d0);
  *(float4*)(bb + 4) = *(const float4*)(b + d0 + 4);
  float y[8]; bf16x8 yb;
#pragma unroll
  for (int i = 0; i < 8; i++) {
    y[i] = x[i] * inv * gg[i] + bb[i];
    yb[i] = (__bf16)y[i];
  }
  if (Xout) {
    *(float4*)(Xout + base)     = *(float4*)y;
    *(float4*)(Xout + base + 4) = *(float4*)(y + 4);
  }
  *(bf16x8*)(Xbout + base) = yb;
}

// ---------------------------------------------------------------------------
extern "C" void kernel_launch(void* const* d_in, const int* in_sizes, int n_in,
                              void* d_out, int out_size, void* d_ws, size_t ws_size,
                              hipStream_t stream)
{
  (void)in_sizes; (void)n_in; (void)out_size; (void)ws_size;
  const float* src_emb    = (const float*)d_in[0];
  const float* tgt_emb    = (const float*)d_in[1];
  const float* enc_attn_w = (const float*)d_in[2];
  const float* enc_attn_b = (const float*)d_in[3];
  const float* enc_ffn_w1 = (const float*)d_in[4];
  const float* enc_ffn_b1 = (const float*)d_in[5];
  const float* enc_ffn_w2 = (const float*)d_in[6];
  const float* enc_ffn_b2 = (const float*)d_in[7];
  const float* enc_ln_g   = (const float*)d_in[8];
  const float* enc_ln_b   = (const float*)d_in[9];
  const float* enc_fg     = (const float*)d_in[10];
  const float* enc_fb     = (const float*)d_in[11];
  const float* dec_self_w = (const float*)d_in[12];
  const float* dec_self_b = (const float*)d_in[13];
  const float* dec_src_w  = (const float*)d_in[14];
  const float* dec_src_b  = (const float*)d_in[15];
  const float* dec_ffn_w1 = (const float*)d_in[16];
  const float* dec_ffn_b1 = (const float*)d_in[17];
  const float* dec_ffn_w2 = (const float*)d_in[18];
  const float* dec_ffn_b2 = (const float*)d_in[19];
  const float* dec_ln_g   = (const float*)d_in[20];
  const float* dec_ln_b   = (const float*)d_in[21];
  const float* dec_fg     = (const float*)d_in[22];
  const float* dec_fb     = (const float*)d_in[23];
  const float* gen_w      = (const float*)d_in[24];
  const float* gen_b      = (const float*)d_in[25];
  const int*   src        = (const int*)d_in[26];
  const int*   tgt        = (const int*)d_in[27];
  const int*   src_mask   = (const int*)d_in[28];

  float* out = (float*)d_out;

  // ---- workspace (~130 MB) ----
  char* wp = (char*)d_ws;
  auto alloc = [&](size_t bytes) { void* p = (void*)wp; wp += (bytes + 255) & ~(size_t)255; return p; };
  __bf16* TWea = (__bf16*)alloc(24ull * 262144 * 2);    // enc attn [6][4][512][512]^T
  __bf16* TWe1 = (__bf16*)alloc(6ull * 1048576 * 2);
  __bf16* TWe2 = (__bf16*)alloc(6ull * 1048576 * 2);
  __bf16* TWds = (__bf16*)alloc(24ull * 262144 * 2);
  __bf16* TWdx = (__bf16*)alloc(24ull * 262144 * 2);
  __bf16* TWd1 = (__bf16*)alloc(6ull * 1048576 * 2);
  __bf16* TWd2 = (__bf16*)alloc(6ull * 1048576 * 2);
  float*  X    = (float*) alloc(4096ull * 512 * 4);
  __bf16* Xb   = (__bf16*)alloc(4096ull * 512 * 2);
  __bf16* MEMb = (__bf16*)alloc(4096ull * 512 * 2);
  float*  R    = (float*) alloc(4096ull * 512 * 4);
  __bf16* qb   = (__bf16*)alloc(32ull * 1024 * 64 * 2); // } union with Fb
  __bf16* kb   = (__bf16*)alloc(32ull * 1024 * 64 * 2);
  __bf16* vt   = (__bf16*)alloc(32ull * 1024 * 64 * 2);
  __bf16* Ob   = (__bf16*)alloc(4096ull * 512 * 2);
  __bf16* Fb   = qb;                                    // ffn hidden bf16 [4096][2048]
  __bf16* GENT = TWea;                                  // gen_w^T, after encoder

  // ---- bulk weight transposes ----
  transpose_w_kernel<<<dim3(16, 16, 24), dim3(32, 8), 0, stream>>>(enc_attn_w, TWea, 512, 512);
  transpose_w_kernel<<<dim3(64, 16, 6),  dim3(32, 8), 0, stream>>>(enc_ffn_w1, TWe1, 512, 2048);
  transpose_w_kernel<<<dim3(16, 64, 6),  dim3(32, 8), 0, stream>>>(enc_ffn_w2, TWe2, 2048, 512);
  transpose_w_kernel<<<dim3(16, 16, 24), dim3(32, 8), 0, stream>>>(dec_self_w, TWds, 512, 512);
  transpose_w_kernel<<<dim3(16, 16, 24), dim3(32, 8), 0, stream>>>(dec_src_w,  TWdx, 512, 512);
  transpose_w_kernel<<<dim3(64, 16, 6),  dim3(32, 8), 0, stream>>>(dec_ffn_w1, TWd1, 512, 2048);
  transpose_w_kernel<<<dim3(16, 64, 6),  dim3(32, 8), 0, stream>>>(dec_ffn_w2, TWd2, 2048, 512);

  // attention sublayer: wt = 4 transposed weights [2048][512]; writes R.
  auto attention = [&](const __bf16* wt, const float* bptr, int causal,
                       const __bf16* Aq, const __bf16* Akv) {
    if (Aq == Akv) {
      // merged QKV: N=1536 (q,k,v weight rows contiguous)
      gemm_kernel<128, 128, 64, 2><<<dim3(32, 12, 1), 256, 0, stream>>>(
          Aq, 512, wt, 512, nullptr, 0, bptr, 512, qb, kb, vt, 0);
    } else {
      gemm_kernel<128, 64, 64, 2><<<dim3(32, 8, 1), 256, 0, stream>>>(
          Aq, 512, wt, 512, nullptr, 0, bptr, 512, qb, kb, vt, 0);
      // merged KV: N=1024 from same A (= memory)
      gemm_kernel<128, 64, 64, 2><<<dim3(32, 16, 1), 256, 0, stream>>>(
          Akv, 512, wt + 262144, 512, nullptr, 0, bptr + 512, 512, qb, kb, vt, 1);
    }
    if (causal)
      flash_kernel<1><<<dim3(16, 32), 256, 0, stream>>>(qb, kb, vt, nullptr, Ob);
    else
      flash_kernel<0><<<dim3(16, 32), 256, 0, stream>>>(qb, kb, vt, src_mask, Ob);
    gemm_kernel<128, 64, 64, 0><<<dim3(32, 8, 1), 256, 0, stream>>>(
        Ob, 512, wt + 3 * 262144, 512, R, 512, bptr + 3 * 512, 512,
        nullptr, nullptr, nullptr, 0);
  };

  auto ffn = [&](const __bf16* w1t, const float* b1, const __bf16* w2t, const float* b2) {
    gemm256_kernel<1><<<dim3(16, 8), 512, 0, stream>>>(
        Xb, 512, w1t, 512, Fb, 2048, b1, 512);
    gemm_kernel<128, 64, 64, 0><<<dim3(32, 8, 1), 256, 0, stream>>>(
        Fb, 2048, w2t, 2048, R, 512, b2, 2048, nullptr, nullptr, nullptr, 0);
  };

  // ---------------- encoder ----------------
  embed_kernel<<<4096, 128, 0, stream>>>(src_emb, src, X, Xb);
  for (int i = 0; i < 6; i++) {
    attention(TWea + (long long)i * 1048576, enc_attn_b + i * 2048, 0, Xb, Xb);
    ln_kernel<<<4096, 64, 0, stream>>>(X, R, enc_ln_g + i * 1024, enc_ln_b + i * 1024, X, Xb);
    ffn(TWe1 + (long long)i * 1048576, enc_ffn_b1 + i * 2048,
        TWe2 + (long long)i * 1048576, enc_ffn_b2 + i * 512);
    ln_kernel<<<4096, 64, 0, stream>>>(X, R, enc_ln_g + i * 1024 + 512, enc_ln_b + i * 1024 + 512, X, Xb);
  }
  ln_kernel<<<4096, 64, 0, stream>>>(X, nullptr, enc_fg, enc_fb, nullptr, MEMb);

  transpose_w_kernel<<<dim3(1000, 16, 1), dim3(32, 8), 0, stream>>>(gen_w, GENT, 512, 32000);

  // ---------------- decoder ----------------
  embed_kernel<<<4096, 128, 0, stream>>>(tgt_emb, tgt, X, Xb);
  for (int i = 0; i < 6; i++) {
    attention(TWds + (long long)i * 1048576, dec_self_b + i * 2048, 1, Xb, Xb);
    ln_kernel<<<4096, 64, 0, stream>>>(X, R, dec_ln_g + i * 1536, dec_ln_b + i * 1536, X, Xb);

    attention(TWdx + (long long)i * 1048576, dec_src_b + i * 2048, 0, Xb, MEMb);
    ln_kernel<<<4096, 64, 0, stream>>>(X, R, dec_ln_g + i * 1536 + 512, dec_ln_b + i * 1536 + 512, X, Xb);

    ffn(TWd1 + (long long)i * 1048576, dec_ffn_b1 + i * 2048,
        TWd2 + (long long)i * 1048576, dec_ffn_b2 + i * 512);
    ln_kernel<<<4096, 64, 0, stream>>>(X, R, dec_ln_g + i * 1536 + 1024, dec_ln_b + i * 1536 + 1024, X, Xb);
  }
  ln_kernel<<<4096, 64, 0, stream>>>(X, nullptr, dec_fg, dec_fb, nullptr, Xb);

  // ---------------- generator: 8-phase 256^2 ----------------
  gemm256_kernel<0><<<dim3(16, 125), 512, 0, stream>>>(
      Xb, 512, GENT, 512, out, 32000, gen_b, 512);
}

// Round 5
// 2076.316 us; speedup vs baseline: 2.2061x; 1.1765x over previous
//
#include <hip/hip_runtime.h>

// ---------------------------------------------------------------------------
// Transformer (enc-dec, D=512, H=8, N=6, DFF=2048, B=4, S=T=1024, V=32000)
// PIPE3 GEMM fleet: 128x64 tile, BK=64, 3 LDS slots, counted vmcnt(6) (never
// 0 in-loop), one raw s_barrier per K-tile, T2 XOR swizzle (both-sides).
// Fused flash attention; fp32 residual/LN; bulk weight transposes.
// ---------------------------------------------------------------------------

typedef __bf16 bf16x8 __attribute__((ext_vector_type(8)));
typedef __bf16 bf16x4 __attribute__((ext_vector_type(4)));
typedef float  f32x4  __attribute__((ext_vector_type(4)));

__device__ __forceinline__ void gload_lds16(const void* g, void* l) {
  __builtin_amdgcn_global_load_lds((__attribute__((address_space(1))) void*)g,
                                   (__attribute__((address_space(3))) void*)l,
                                   16, 0, 0);
}

__device__ __forceinline__ void hard_barrier() {
  asm volatile("" ::: "memory");
  __builtin_amdgcn_sched_barrier(0);
  __builtin_amdgcn_s_barrier();
  __builtin_amdgcn_sched_barrier(0);
  asm volatile("" ::: "memory");
}

// ---------------------------------------------------------------------------
// PIPE3 GEMM: C = A[M,K] @ BT[N,K]^T + bias. A,BT bf16 row-major.
// 256 thr, 4 waves (2x2), tile 128x64, BK=64. 3 swizzled LDS slots.
// EPI 0: C fp32 + bias. EPI 1: C bf16 + bias + ReLU. EPI 2: qkv head routing.
template<int EPI>
__global__ __launch_bounds__(256)
void gemm_kernel(const __bf16* __restrict__ A, int lda,
                 const __bf16* __restrict__ BT, int ldb,
                 void* __restrict__ Cv, int ldc,
                 const float* __restrict__ bias, int K,
                 __bf16* __restrict__ qb, __bf16* __restrict__ kb,
                 __bf16* __restrict__ vt, int zoff)
{
  constexpr int BM = 128, BN = 64, BK = 64;
  constexpr int WM = 64, WN = 32, FM = 4, FN = 2;
  constexpr int LA = (BM * BK) / 2048;         // 4 insts/thread
  constexpr int LB = (BN * BK) / 2048;         // 2 insts/thread
  constexpr int SLOT = (BM + BN) * BK;         // elements per slot
  __shared__ __bf16 lds[3 * SLOT];             // 72 KB
  const int tid  = threadIdx.x;
  const int lane = tid & 63, wave = tid >> 6;
  const int wr = wave >> 1, wc = wave & 1;
  const int bm = blockIdx.x * BM, bn = blockIdx.y * BN;

  // linear LDS dest + inverse-swizzled global source (rule #21)
  auto stage = [&](int slot, int kt) {
    const char* Ag = (const char*)A;
    const char* Bg = (const char*)BT;
    char* base = (char*)(lds + slot * SLOT);
    const long long k0b = (long long)kt * (BK * 2);
#pragma unroll
    for (int i = 0; i < LA; i++) {
      int t = tid + i * 256;                   // 0..1023
      int row = t >> 3, cb = (t & 7) << 4;
      int src = cb ^ ((row & 7) << 4);
      gload_lds16(Ag + ((long long)(bm + row) * lda) * 2 + k0b + src, base + t * 16);
    }
#pragma unroll
    for (int i = 0; i < LB; i++) {
      int t = tid + i * 256;                   // 0..511
      int row = t >> 3, cb = (t & 7) << 4;
      int src = cb ^ ((row & 7) << 4);
      gload_lds16(Bg + ((long long)(bn + row) * ldb) * 2 + k0b + src,
                  base + BM * BK * 2 + t * 16);
    }
  };

  f32x4 acc[FM][FN] = {};
  const int NT = K / BK;                       // >= 2 everywhere

  stage(0, 0);
  stage(1, 1);

  for (int t = 0; t < NT; t++) {
    if (t < NT - 1) {
      asm volatile("s_waitcnt vmcnt(6)" ::: "memory");   // own tile-t loads done
    } else {
      asm volatile("s_waitcnt vmcnt(0)" ::: "memory");
    }
    hard_barrier();                            // all waves' tile-t portions visible
    if (t + 2 < NT) stage((t + 2) % 3, t + 2); // slot (t-1)%3: released by barrier
    const char* sA = (const char*)(lds + (t % 3) * SLOT);
    const char* sB = sA + BM * BK * 2;
#pragma unroll
    for (int kk = 0; kk < 2; kk++) {
      const int g = kk * 64 + (lane >> 4) * 16;  // byte offset in 128-B row
      bf16x8 af[FM], bfr[FN];
#pragma unroll
      for (int i = 0; i < FM; i++) {
        int row = wr * WM + i * 16 + (lane & 15);
        af[i] = *(const bf16x8*)(sA + row * 128 + (g ^ ((row & 7) << 4)));
      }
#pragma unroll
      for (int j = 0; j < FN; j++) {
        int row = wc * WN + j * 16 + (lane & 15);
        bfr[j] = *(const bf16x8*)(sB + row * 128 + (g ^ ((row & 7) << 4)));
      }
      __builtin_amdgcn_s_setprio(1);
#pragma unroll
      for (int i = 0; i < FM; i++)
#pragma unroll
        for (int j = 0; j < FN; j++)
          acc[i][j] = __builtin_amdgcn_mfma_f32_16x16x32_bf16(af[i], bfr[j], acc[i][j], 0, 0, 0);
      __builtin_amdgcn_s_setprio(0);
    }
  }

#pragma unroll
  for (int i = 0; i < FM; i++) {
#pragma unroll
    for (int j = 0; j < FN; j++) {
      int row0 = bm + wr * WM + i * 16 + (lane >> 4) * 4;
      int col  = bn + wc * WN + j * 16 + (lane & 15);
      float bv = bias ? bias[col] : 0.f;
      if constexpr (EPI == 2) {
        int z = zoff + (col >> 9);
        int cw = col & 511;
        int b = row0 >> 10, s = row0 & 1023;
        int h = cw >> 6, dk = cw & 63;
        long long bh = b * 8 + h;
        if (z == 2) {
          bf16x4 vv;
#pragma unroll
          for (int r = 0; r < 4; r++) vv[r] = (__bf16)(acc[i][j][r] + bv);
          *(bf16x4*)(vt + (bh << 16) + (dk << 10) + s) = vv;
        } else {
          __bf16* dst = (z == 0) ? qb : kb;
          float sc = (z == 0) ? 0.125f : 1.0f;
#pragma unroll
          for (int r = 0; r < 4; r++)
            dst[(bh << 16) + ((long long)(s + r) << 6) + dk] = (__bf16)((acc[i][j][r] + bv) * sc);
        }
      } else if constexpr (EPI == 1) {
        __bf16* C = (__bf16*)Cv;
#pragma unroll
        for (int r = 0; r < 4; r++)
          C[(long long)(row0 + r) * ldc + col] = (__bf16)fmaxf(acc[i][j][r] + bv, 0.f);
      } else {
        float* C = (float*)Cv;
#pragma unroll
        for (int r = 0; r < 4; r++)
          C[(long long)(row0 + r) * ldc + col] = acc[i][j][r] + bv;
      }
    }
  }
}

// ---------------------------------------------------------------------------
// Flash attention (unchanged): per block one (bh, 64-row q-tile).
template<int CAUSAL>
__global__ __launch_bounds__(256)
void flash_kernel(const __bf16* __restrict__ qb, const __bf16* __restrict__ kb,
                  const __bf16* __restrict__ vt, const int* __restrict__ smask,
                  __bf16* __restrict__ Ob)
{
  __shared__ __bf16 lK[2 * 128 * 64];
  __shared__ __bf16 lV[2 * 64 * 128];
  __shared__ __bf16 lP[4][16 * 128];
  const int bh = blockIdx.y;
  const int b = bh >> 3, h = bh & 7;
  const int q0 = blockIdx.x * 64;
  const int tid = threadIdx.x, lane = tid & 63, w = tid >> 6;
  const char* kh = (const char*)(kb + ((long long)bh << 16));
  const char* vh = (const char*)(vt + ((long long)bh << 16));

  auto stageKV = [&](int buf, int t) {
    int k0 = t * 128;
#pragma unroll
    for (int i = 0; i < 4; i++) {
      int c = tid + i * 256;
      int row = c >> 3, cb = (c & 7) << 4;
      int cl = cb ^ ((row & 7) << 4);
      gload_lds16(kh + (long long)(k0 + row) * 128 + cl, (char*)lK + buf * 16384 + c * 16);
    }
#pragma unroll
    for (int i = 0; i < 4; i++) {
      int c = tid + i * 256;
      int row = c >> 4, cb = (c & 15) << 4;
      int cl = cb ^ ((row & 7) << 4);
      gload_lds16(vh + (long long)row * 2048 + (long long)k0 * 2 + cl, (char*)lV + buf * 16384 + c * 16);
    }
  };

  bf16x8 qa[2];
  {
    const __bf16* qrow = qb + ((long long)bh << 16)
                       + (long long)(q0 + w * 16 + (lane & 15)) * 64 + (lane >> 4) * 8;
    qa[0] = *(const bf16x8*)(qrow);
    qa[1] = *(const bf16x8*)(qrow + 32);
  }
  f32x4 oacc[4] = {};
  float m[4], l[4];
#pragma unroll
  for (int r = 0; r < 4; r++) { m[r] = -3e38f; l[r] = 0.f; }

  const int nt = CAUSAL ? (blockIdx.x / 2 + 1) : 8;
  char* lPw = (char*)lP + w * 4096;
  stageKV(0, 0);

  for (int t = 0; t < nt; t++) {
    const int k0 = t * 128;
    __syncthreads();
    if (t + 1 < nt) stageKV((t + 1) & 1, t + 1);
    char* cK = (char*)lK + (t & 1) * 16384;
    char* cV = (char*)lV + (t & 1) * 16384;

    f32x4 sf[8];
#pragma unroll
    for (int f = 0; f < 8; f++) {
      int row = f * 16 + (lane & 15);
      f32x4 s = {};
#pragma unroll
      for (int ks = 0; ks < 2; ks++) {
        int cb = ks * 64 + (lane >> 4) * 16;
        bf16x8 kf = *(const bf16x8*)(cK + row * 128 + (cb ^ ((row & 7) << 4)));
        s = __builtin_amdgcn_mfma_f32_16x16x32_bf16(qa[ks], kf, s, 0, 0, 0);
      }
      sf[f] = s;
    }

    if (!CAUSAL) {
#pragma unroll
      for (int f = 0; f < 8; f++) {
        if (smask[b * 1024 + k0 + f * 16 + (lane & 15)] == 0) {
#pragma unroll
          for (int r = 0; r < 4; r++) sf[f][r] = -1e30f;
        }
      }
    } else if (t == nt - 1) {
#pragma unroll
      for (int f = 0; f < 8; f++) {
        int kc = k0 + f * 16 + (lane & 15);
#pragma unroll
        for (int r = 0; r < 4; r++) {
          int qr = q0 + w * 16 + (lane >> 4) * 4 + r;
          if (kc > qr) sf[f][r] = -1e30f;
        }
      }
    }

    float mt[4], mn[4], cr[4], rs[4];
#pragma unroll
    for (int r = 0; r < 4; r++) {
      float v = sf[0][r];
#pragma unroll
      for (int f = 1; f < 8; f++) v = fmaxf(v, sf[f][r]);
      mt[r] = v;
    }
#pragma unroll
    for (int o = 1; o < 16; o <<= 1)
#pragma unroll
      for (int r = 0; r < 4; r++) mt[r] = fmaxf(mt[r], __shfl_xor(mt[r], o));
#pragma unroll
    for (int r = 0; r < 4; r++) {
      mn[r] = fmaxf(m[r], mt[r]);
      cr[r] = __expf(m[r] - mn[r]);
      m[r]  = mn[r];
      rs[r] = 0.f;
    }
#pragma unroll
    for (int f = 0; f < 8; f++)
#pragma unroll
      for (int r = 0; r < 4; r++) {
        float p = __expf(sf[f][r] - mn[r]);
        sf[f][r] = p;
        rs[r] += p;
      }
#pragma unroll
    for (int o = 1; o < 16; o <<= 1)
#pragma unroll
      for (int r = 0; r < 4; r++) rs[r] += __shfl_xor(rs[r], o);
#pragma unroll
    for (int r = 0; r < 4; r++) l[r] = l[r] * cr[r] + rs[r];
#pragma unroll
    for (int d = 0; d < 4; d++)
#pragma unroll
      for (int r = 0; r < 4; r++) oacc[d][r] *= cr[r];

#pragma unroll
    for (int f = 0; f < 8; f++) {
      int colB = f * 32 + (lane & 15) * 2;
#pragma unroll
      for (int r = 0; r < 4; r++) {
        int row = (lane >> 4) * 4 + r;
        *(__bf16*)(lPw + row * 256 + (colB ^ ((row & 7) << 4))) = (__bf16)sf[f][r];
      }
    }
    asm volatile("s_waitcnt lgkmcnt(0)" ::: "memory");

#pragma unroll
    for (int ks = 0; ks < 4; ks++) {
      int prow = lane & 15;
      int cb = ks * 64 + (lane >> 4) * 16;
      bf16x8 pa = *(const bf16x8*)(lPw + prow * 256 + (cb ^ ((prow & 7) << 4)));
#pragma unroll
      for (int d = 0; d < 4; d++) {
        int vrow = d * 16 + (lane & 15);
        bf16x8 vf = *(const bf16x8*)(cV + vrow * 256 + (cb ^ ((vrow & 7) << 4)));
        oacc[d] = __builtin_amdgcn_mfma_f32_16x16x32_bf16(pa, vf, oacc[d], 0, 0, 0);
      }
    }
  }

  float inv[4];
#pragma unroll
  for (int r = 0; r < 4; r++) inv[r] = 1.f / l[r];
#pragma unroll
  for (int d = 0; d < 4; d++)
#pragma unroll
    for (int r = 0; r < 4; r++) {
      long long row = b * 1024 + q0 + w * 16 + (lane >> 4) * 4 + r;
      Ob[row * 512 + h * 64 + d * 16 + (lane & 15)] = (__bf16)(oacc[d][r] * inv[r]);
    }
}

// ---------------------------------------------------------------------------
__global__ void transpose_w_kernel(const float* __restrict__ W, __bf16* __restrict__ WT,
                                   int K, int N)
{
  __shared__ float t[32][33];
  long long mz = (long long)blockIdx.z * K * N;
  W += mz; WT += mz;
  int n0 = blockIdx.x * 32, k0 = blockIdx.y * 32;
  int tx = threadIdx.x, ty = threadIdx.y;
#pragma unroll
  for (int i = 0; i < 32; i += 8)
    t[ty + i][tx] = W[(long long)(k0 + ty + i) * N + (n0 + tx)];
  __syncthreads();
#pragma unroll
  for (int i = 0; i < 32; i += 8)
    WT[(long long)(n0 + ty + i) * K + (k0 + tx)] = (__bf16)t[tx][ty + i];
}

__global__ void embed_kernel(const float* __restrict__ emb, const int* __restrict__ idx,
                             float* __restrict__ X, __bf16* __restrict__ Xb)
{
  int row = blockIdx.x;
  int s   = row & 1023;
  int tok = idx[row];
  int d0  = threadIdx.x * 4;
  float4 e = *(const float4*)(emb + (long long)tok * 512 + d0);
  const float* ep = (const float*)&e;
  float o[4];
#pragma unroll
  for (int j = 0; j < 4; j++) {
    int d = d0 + j;
    float div = expf((float)(d & ~1) * (-9.210340371976184f / 512.f));
    float ang = (float)s * div;
    float pe  = (d & 1) ? cosf(ang) : sinf(ang);
    o[j] = ep[j] + pe;
  }
  *(float4*)(X + (long long)row * 512 + d0) = *(float4*)o;
  bf16x4 ob;
#pragma unroll
  for (int j = 0; j < 4; j++) ob[j] = (__bf16)o[j];
  *(bf16x4*)(Xb + (long long)row * 512 + d0) = ob;
}

__global__ void ln_kernel(const float* __restrict__ Xin, const float* __restrict__ Rin,
                          const float* __restrict__ g, const float* __restrict__ b,
                          float* __restrict__ Xout, __bf16* __restrict__ Xbout)
{
  int row = blockIdx.x, lane = threadIdx.x;
  long long base = (long long)row * 512 + lane * 8;
  float x[8];
  *(float4*)x       = *(const float4*)(Xin + base);
  *(float4*)(x + 4) = *(const float4*)(Xin + base + 4);
  if (Rin) {
    float4 r0 = *(const float4*)(Rin + base);
    float4 r1 = *(const float4*)(Rin + base + 4);
    x[0] += r0.x; x[1] += r0.y; x[2] += r0.z; x[3] += r0.w;
    x[4] += r1.x; x[5] += r1.y; x[6] += r1.z; x[7] += r1.w;
  }
  float s = 0.f;
#pragma unroll
  for (int i = 0; i < 8; i++) s += x[i];
#pragma unroll
  for (int o = 32; o > 0; o >>= 1) s += __shfl_xor(s, o);
  float mean = s * (1.f / 512.f);
  float v = 0.f;
#pragma unroll
  for (int i = 0; i < 8; i++) { x[i] -= mean; v += x[i] * x[i]; }
#pragma unroll
  for (int o = 32; o > 0; o >>= 1) v += __shfl_xor(v, o);
  float inv = rsqrtf(v * (1.f / 512.f) + 1e-5f);
  int d0 = lane * 8;
  float gg[8], bb[8];
  *(float4*)gg       = *(const float4*)(g + d0);
  *(float4*)(gg + 4) = *(const float4*)(g + d0 + 4);
  *(float4*)bb       = *(const float4*)(b + d0);
  *(float4*)(bb + 4) = *(const float4*)(b + d0 + 4);
  float y[8]; bf16x8 yb;
#pragma unroll
  for (int i = 0; i < 8; i++) {
    y[i] = x[i] * inv * gg[i] + bb[i];
    yb[i] = (__bf16)y[i];
  }
  if (Xout) {
    *(float4*)(Xout + base)     = *(float4*)y;
    *(float4*)(Xout + base + 4) = *(float4*)(y + 4);
  }
  *(bf16x8*)(Xbout + base) = yb;
}

// ---------------------------------------------------------------------------
extern "C" void kernel_launch(void* const* d_in, const int* in_sizes, int n_in,
                              void* d_out, int out_size, void* d_ws, size_t ws_size,
                              hipStream_t stream)
{
  (void)in_sizes; (void)n_in; (void)out_size; (void)ws_size;
  const float* src_emb    = (const float*)d_in[0];
  const float* tgt_emb    = (const float*)d_in[1];
  const float* enc_attn_w = (const float*)d_in[2];
  const float* enc_attn_b = (const float*)d_in[3];
  const float* enc_ffn_w1 = (const float*)d_in[4];
  const float* enc_ffn_b1 = (const float*)d_in[5];
  const float* enc_ffn_w2 = (const float*)d_in[6];
  const float* enc_ffn_b2 = (const float*)d_in[7];
  const float* enc_ln_g   = (const float*)d_in[8];
  const float* enc_ln_b   = (const float*)d_in[9];
  const float* enc_fg     = (const float*)d_in[10];
  const float* enc_fb     = (const float*)d_in[11];
  const float* dec_self_w = (const float*)d_in[12];
  const float* dec_self_b = (const float*)d_in[13];
  const float* dec_src_w  = (const float*)d_in[14];
  const float* dec_src_b  = (const float*)d_in[15];
  const float* dec_ffn_w1 = (const float*)d_in[16];
  const float* dec_ffn_b1 = (const float*)d_in[17];
  const float* dec_ffn_w2 = (const float*)d_in[18];
  const float* dec_ffn_b2 = (const float*)d_in[19];
  const float* dec_ln_g   = (const float*)d_in[20];
  const float* dec_ln_b   = (const float*)d_in[21];
  const float* dec_fg     = (const float*)d_in[22];
  const float* dec_fb     = (const float*)d_in[23];
  const float* gen_w      = (const float*)d_in[24];
  const float* gen_b      = (const float*)d_in[25];
  const int*   src        = (const int*)d_in[26];
  const int*   tgt        = (const int*)d_in[27];
  const int*   src_mask   = (const int*)d_in[28];

  float* out = (float*)d_out;

  // ---- workspace (~130 MB) ----
  char* wp = (char*)d_ws;
  auto alloc = [&](size_t bytes) { void* p = (void*)wp; wp += (bytes + 255) & ~(size_t)255; return p; };
  __bf16* TWea = (__bf16*)alloc(24ull * 262144 * 2);    // enc attn [6][4][512][512]^T
  __bf16* TWe1 = (__bf16*)alloc(6ull * 1048576 * 2);
  __bf16* TWe2 = (__bf16*)alloc(6ull * 1048576 * 2);
  __bf16* TWds = (__bf16*)alloc(24ull * 262144 * 2);
  __bf16* TWdx = (__bf16*)alloc(24ull * 262144 * 2);
  __bf16* TWd1 = (__bf16*)alloc(6ull * 1048576 * 2);
  __bf16* TWd2 = (__bf16*)alloc(6ull * 1048576 * 2);
  float*  X    = (float*) alloc(4096ull * 512 * 4);
  __bf16* Xb   = (__bf16*)alloc(4096ull * 512 * 2);
  __bf16* MEMb = (__bf16*)alloc(4096ull * 512 * 2);
  float*  R    = (float*) alloc(4096ull * 512 * 4);
  __bf16* qb   = (__bf16*)alloc(32ull * 1024 * 64 * 2); // } union with Fb
  __bf16* kb   = (__bf16*)alloc(32ull * 1024 * 64 * 2);
  __bf16* vt   = (__bf16*)alloc(32ull * 1024 * 64 * 2);
  __bf16* Ob   = (__bf16*)alloc(4096ull * 512 * 2);
  __bf16* Fb   = qb;                                    // ffn hidden bf16 [4096][2048]
  __bf16* GENT = TWea;                                  // gen_w^T, after encoder

  // ---- bulk weight transposes ----
  transpose_w_kernel<<<dim3(16, 16, 24), dim3(32, 8), 0, stream>>>(enc_attn_w, TWea, 512, 512);
  transpose_w_kernel<<<dim3(64, 16, 6),  dim3(32, 8), 0, stream>>>(enc_ffn_w1, TWe1, 512, 2048);
  transpose_w_kernel<<<dim3(16, 64, 6),  dim3(32, 8), 0, stream>>>(enc_ffn_w2, TWe2, 2048, 512);
  transpose_w_kernel<<<dim3(16, 16, 24), dim3(32, 8), 0, stream>>>(dec_self_w, TWds, 512, 512);
  transpose_w_kernel<<<dim3(16, 16, 24), dim3(32, 8), 0, stream>>>(dec_src_w,  TWdx, 512, 512);
  transpose_w_kernel<<<dim3(64, 16, 6),  dim3(32, 8), 0, stream>>>(dec_ffn_w1, TWd1, 512, 2048);
  transpose_w_kernel<<<dim3(16, 64, 6),  dim3(32, 8), 0, stream>>>(dec_ffn_w2, TWd2, 2048, 512);

  // attention sublayer: wt = 4 transposed weights [2048][512]; writes R.
  auto attention = [&](const __bf16* wt, const float* bptr, int causal,
                       const __bf16* Aq, const __bf16* Akv) {
    if (Aq == Akv) {
      gemm_kernel<2><<<dim3(32, 24), 256, 0, stream>>>(        // merged QKV N=1536
          Aq, 512, wt, 512, nullptr, 0, bptr, 512, qb, kb, vt, 0);
    } else {
      gemm_kernel<2><<<dim3(32, 8), 256, 0, stream>>>(          // Q only
          Aq, 512, wt, 512, nullptr, 0, bptr, 512, qb, kb, vt, 0);
      gemm_kernel<2><<<dim3(32, 16), 256, 0, stream>>>(         // merged KV N=1024
          Akv, 512, wt + 262144, 512, nullptr, 0, bptr + 512, 512, qb, kb, vt, 1);
    }
    if (causal)
      flash_kernel<1><<<dim3(16, 32), 256, 0, stream>>>(qb, kb, vt, nullptr, Ob);
    else
      flash_kernel<0><<<dim3(16, 32), 256, 0, stream>>>(qb, kb, vt, src_mask, Ob);
    gemm_kernel<0><<<dim3(32, 8), 256, 0, stream>>>(
        Ob, 512, wt + 3 * 262144, 512, R, 512, bptr + 3 * 512, 512,
        nullptr, nullptr, nullptr, 0);
  };

  auto ffn = [&](const __bf16* w1t, const float* b1, const __bf16* w2t, const float* b2) {
    gemm_kernel<1><<<dim3(32, 32), 256, 0, stream>>>(
        Xb, 512, w1t, 512, Fb, 2048, b1, 512, nullptr, nullptr, nullptr, 0);
    gemm_kernel<0><<<dim3(32, 8), 256, 0, stream>>>(
        Fb, 2048, w2t, 2048, R, 512, b2, 2048, nullptr, nullptr, nullptr, 0);
  };

  // ---------------- encoder ----------------
  embed_kernel<<<4096, 128, 0, stream>>>(src_emb, src, X, Xb);
  for (int i = 0; i < 6; i++) {
    attention(TWea + (long long)i * 1048576, enc_attn_b + i * 2048, 0, Xb, Xb);
    ln_kernel<<<4096, 64, 0, stream>>>(X, R, enc_ln_g + i * 1024, enc_ln_b + i * 1024, X, Xb);
    ffn(TWe1 + (long long)i * 1048576, enc_ffn_b1 + i * 2048,
        TWe2 + (long long)i * 1048576, enc_ffn_b2 + i * 512);
    ln_kernel<<<4096, 64, 0, stream>>>(X, R, enc_ln_g + i * 1024 + 512, enc_ln_b + i * 1024 + 512, X, Xb);
  }
  ln_kernel<<<4096, 64, 0, stream>>>(X, nullptr, enc_fg, enc_fb, nullptr, MEMb);

  transpose_w_kernel<<<dim3(1000, 16, 1), dim3(32, 8), 0, stream>>>(gen_w, GENT, 512, 32000);

  // ---------------- decoder ----------------
  embed_kernel<<<4096, 128, 0, stream>>>(tgt_emb, tgt, X, Xb);
  for (int i = 0; i < 6; i++) {
    attention(TWds + (long long)i * 1048576, dec_self_b + i * 2048, 1, Xb, Xb);
    ln_kernel<<<4096, 64, 0, stream>>>(X, R, dec_ln_g + i * 1536, dec_ln_b + i * 1536, X, Xb);

    attention(TWdx + (long long)i * 1048576, dec_src_b + i * 2048, 0, Xb, MEMb);
    ln_kernel<<<4096, 64, 0, stream>>>(X, R, dec_ln_g + i * 1536 + 512, dec_ln_b + i * 1536 + 512, X, Xb);

    ffn(TWd1 + (long long)i * 1048576, dec_ffn_b1 + i * 2048,
        TWd2 + (long long)i * 1048576, dec_ffn_b2 + i * 512);
    ln_kernel<<<4096, 64, 0, stream>>>(X, R, dec_ln_g + i * 1536 + 1024, dec_ln_b + i * 1536 + 1024, X, Xb);
  }
  ln_kernel<<<4096, 64, 0, stream>>>(X, nullptr, dec_fg, dec_fb, nullptr, Xb);

  // ---------------- generator ----------------
  gemm_kernel<0><<<dim3(32, 500), 256, 0, stream>>>(
      Xb, 512, GENT, 512, out, 32000, gen_b, 512, nullptr, nullptr, nullptr, 0);
}